// Round 1
// baseline (49367.249 us; speedup 1.0000x reference)
//
#include <hip/hip_runtime.h>

#define NND 50000
#define NE  1600000
#define EMB 128
#define NH  8
#define HD  16

__device__ __forceinline__ float lrelu(float x) { return x > 0.f ? x : 0.2f * x; }
__device__ __forceinline__ float elu(float x)   { return x > 0.f ? x : expm1f(x); }

// feat = h @ W  (N x 128 @ 128 x 128), fused el/er per-head dots.
// Block: 256 threads, 32 rows per block. Thread t: row r=t>>3, head c8=t&7 (16 cols).
__global__ __launch_bounds__(256) void gemm_feat(
    const float* __restrict__ hin, const float* __restrict__ Wm,
    const float* __restrict__ alv, const float* __restrict__ arv,
    float* __restrict__ feat, float* __restrict__ el, float* __restrict__ er)
{
    __shared__ float A[32][EMB + 1];
    const int tid  = threadIdx.x;
    const int base = blockIdx.x * 32;

    // cooperative load of 32x128 tile (1024 float4s; 4 per thread)
    const float4* h4 = reinterpret_cast<const float4*>(hin);
    #pragma unroll
    for (int i = 0; i < 4; ++i) {
        int idx4 = tid + i * 256;          // 0..1023
        int row  = idx4 >> 5;              // 32 float4 per row
        int c4   = idx4 & 31;
        float4 v = make_float4(0.f, 0.f, 0.f, 0.f);
        if (base + row < NND) v = h4[(size_t)(base + row) * 32 + c4];
        A[row][c4 * 4 + 0] = v.x;
        A[row][c4 * 4 + 1] = v.y;
        A[row][c4 * 4 + 2] = v.z;
        A[row][c4 * 4 + 3] = v.w;
    }
    __syncthreads();

    const int r  = tid >> 3;
    const int c8 = tid & 7;

    float acc[16];
    #pragma unroll
    for (int i = 0; i < 16; ++i) acc[i] = 0.f;

    const float4* W4 = reinterpret_cast<const float4*>(Wm) + c8 * 4;  // row k: W4[k*32 + j]
    #pragma unroll 4
    for (int k = 0; k < 128; ++k) {
        float a = A[r][k];
        float4 w0 = W4[k * 32 + 0];
        float4 w1 = W4[k * 32 + 1];
        float4 w2 = W4[k * 32 + 2];
        float4 w3 = W4[k * 32 + 3];
        acc[0]  = fmaf(a, w0.x, acc[0]);  acc[1]  = fmaf(a, w0.y, acc[1]);
        acc[2]  = fmaf(a, w0.z, acc[2]);  acc[3]  = fmaf(a, w0.w, acc[3]);
        acc[4]  = fmaf(a, w1.x, acc[4]);  acc[5]  = fmaf(a, w1.y, acc[5]);
        acc[6]  = fmaf(a, w1.z, acc[6]);  acc[7]  = fmaf(a, w1.w, acc[7]);
        acc[8]  = fmaf(a, w2.x, acc[8]);  acc[9]  = fmaf(a, w2.y, acc[9]);
        acc[10] = fmaf(a, w2.z, acc[10]); acc[11] = fmaf(a, w2.w, acc[11]);
        acc[12] = fmaf(a, w3.x, acc[12]); acc[13] = fmaf(a, w3.y, acc[13]);
        acc[14] = fmaf(a, w3.z, acc[14]); acc[15] = fmaf(a, w3.w, acc[15]);
    }

    const int row = base + r;
    if (row < NND) {
        float4* f4 = reinterpret_cast<float4*>(feat + (size_t)row * EMB + c8 * 16);
        f4[0] = make_float4(acc[0],  acc[1],  acc[2],  acc[3]);
        f4[1] = make_float4(acc[4],  acc[5],  acc[6],  acc[7]);
        f4[2] = make_float4(acc[8],  acc[9],  acc[10], acc[11]);
        f4[3] = make_float4(acc[12], acc[13], acc[14], acc[15]);
        float sl = 0.f, sr = 0.f;
        #pragma unroll
        for (int i = 0; i < 16; ++i) {
            sl = fmaf(acc[i], alv[c8 * 16 + i], sl);
            sr = fmaf(acc[i], arv[c8 * 16 + i], sr);
        }
        el[row * NH + c8] = sl;
        er[row * NH + c8] = sr;
    }
}

// Pass A: esum[dst][h] += exp(leaky_relu(el[src][h] + er[dst][h]))
__global__ __launch_bounds__(256) void edge_sum(
    const int* __restrict__ src, const int* __restrict__ dst,
    const float* __restrict__ el, const float* __restrict__ er,
    float* __restrict__ esum)
{
    int e = blockIdx.x * blockDim.x + threadIdx.x;
    if (e >= NE) return;
    int s = src[e], d = dst[e];
    const float4* el4 = reinterpret_cast<const float4*>(el);
    const float4* er4 = reinterpret_cast<const float4*>(er);
    float4 a0 = el4[s * 2], a1 = el4[s * 2 + 1];
    float4 b0 = er4[d * 2], b1 = er4[d * 2 + 1];
    float v[8] = { a0.x + b0.x, a0.y + b0.y, a0.z + b0.z, a0.w + b0.w,
                   a1.x + b1.x, a1.y + b1.y, a1.z + b1.z, a1.w + b1.w };
    #pragma unroll
    for (int h = 0; h < 8; ++h) {
        atomicAdd(&esum[(size_t)d * NH + h], expf(lrelu(v[h])));
    }
}

// Pass B: per (edge, head): alpha = exp(e)/esum[dst][h]; rst[dst][h*16+i] += alpha*feat[src][h*16+i]
__global__ __launch_bounds__(256) void scatter(
    const int* __restrict__ src, const int* __restrict__ dst,
    const float* __restrict__ el, const float* __restrict__ er,
    const float* __restrict__ esum, const float* __restrict__ feat,
    float* __restrict__ rst, float* __restrict__ aout)
{
    int tid = blockIdx.x * blockDim.x + threadIdx.x;
    if (tid >= NE * NH) return;
    int e = tid >> 3;
    int h = tid & 7;
    int s = src[e], d = dst[e];
    float x = lrelu(el[(size_t)s * NH + h] + er[(size_t)d * NH + h]);
    float alpha = expf(x) / fmaxf(esum[(size_t)d * NH + h], 1e-9f);
    if (aout) aout[(size_t)e * NH + h] = alpha;
    const float4* f4 = reinterpret_cast<const float4*>(feat + (size_t)s * EMB + h * 16);
    float* rp = rst + (size_t)d * EMB + h * 16;
    #pragma unroll
    for (int i = 0; i < 4; ++i) {
        float4 v = f4[i];
        atomicAdd(rp + i * 4 + 0, alpha * v.x);
        atomicAdd(rp + i * 4 + 1, alpha * v.y);
        atomicAdd(rp + i * 4 + 2, alpha * v.z);
        atomicAdd(rp + i * 4 + 3, alpha * v.w);
    }
}

// h_next = elu(rst + h + bias)
__global__ __launch_bounds__(256) void epilogue(
    const float* __restrict__ rst, const float* __restrict__ hin,
    const float* __restrict__ bias, float* __restrict__ hout)
{
    int idx = blockIdx.x * blockDim.x + threadIdx.x;   // N*32 float4s
    if (idx >= NND * 32) return;
    const float4* r4 = reinterpret_cast<const float4*>(rst);
    const float4* h4 = reinterpret_cast<const float4*>(hin);
    float4 r = r4[idx];
    float4 h = h4[idx];
    int d0 = (idx & 31) * 4;
    float4 o;
    o.x = elu(r.x + h.x + bias[d0 + 0]);
    o.y = elu(r.y + h.y + bias[d0 + 1]);
    o.z = elu(r.z + h.z + bias[d0 + 2]);
    o.w = elu(r.w + h.w + bias[d0 + 3]);
    reinterpret_cast<float4*>(hout)[idx] = o;
}

extern "C" void kernel_launch(void* const* d_in, const int* in_sizes, int n_in,
                              void* d_out, int out_size, void* d_ws, size_t ws_size,
                              hipStream_t stream) {
    const float* fs   = (const float*)d_in[0];  // [2][N][128]
    const float* W    = (const float*)d_in[1];  // [2][2][128][128]
    const float* al   = (const float*)d_in[2];  // [2][2][8][16]
    const float* ar   = (const float*)d_in[3];  // [2][2][8][16]
    const float* bias = (const float*)d_in[4];  // [2][2][128]
    const int*   edges= (const int*)d_in[5];    // [2][2][E]

    float* out       = (float*)d_out;
    float* out_emb   = out;                              // [2][N][128]
    float* out_alpha = out + (size_t)2 * NND * EMB;      // [2][E][8]

    float* ws   = (float*)d_ws;
    float* feat = ws;                         // N*128
    float* rst  = feat + (size_t)NND * EMB;   // N*128
    float* hbuf = rst  + (size_t)NND * EMB;   // N*128
    float* el   = hbuf + (size_t)NND * EMB;   // N*8
    float* er   = el   + (size_t)NND * NH;    // N*8
    float* esum = er   + (size_t)NND * NH;    // N*8

    for (int p = 0; p < 2; ++p) {
        const int* src = edges + (size_t)p * 2 * NE;
        const int* dst = src + NE;
        for (int l = 0; l < 2; ++l) {
            const float* hin  = (l == 0) ? fs + (size_t)p * NND * EMB : hbuf;
            float*       hout = (l == 1) ? out_emb + (size_t)p * NND * EMB : hbuf;
            const float* Wl   = W    + (size_t)(p * 2 + l) * EMB * EMB;
            const float* alv  = al   + (size_t)(p * 2 + l) * NH * HD;
            const float* arv  = ar   + (size_t)(p * 2 + l) * NH * HD;
            const float* bl   = bias + (size_t)(p * 2 + l) * EMB;
            float*       aout = (l == 1) ? out_alpha + (size_t)p * NE * NH : nullptr;

            hipMemsetAsync(esum, 0, (size_t)NND * NH * sizeof(float), stream);
            hipMemsetAsync(rst,  0, (size_t)NND * EMB * sizeof(float), stream);

            gemm_feat<<<(NND + 31) / 32, 256, 0, stream>>>(hin, Wl, alv, arv, feat, el, er);
            edge_sum<<<(NE + 255) / 256, 256, 0, stream>>>(src, dst, el, er, esum);
            scatter<<<((size_t)NE * NH + 255) / 256, 256, 0, stream>>>(src, dst, el, er, esum, feat, rst, aout);
            epilogue<<<(NND * 32 + 255) / 256, 256, 0, stream>>>(rst, hin, bl, hout);
        }
    }
}

// Round 2
// 2081.081 us; speedup vs baseline: 23.7219x; 23.7219x over previous
//
#include <hip/hip_runtime.h>

#define NND 50000
#define NE  1600000
#define EMB 128
#define NH  8
#define HD  16

__device__ __forceinline__ float lrelu(float x) { return x > 0.f ? x : 0.2f * x; }
__device__ __forceinline__ float elu(float x)   { return x > 0.f ? x : expm1f(x); }

// ---------------- GEMM: feat = h @ W, fused el/er per-head dots ----------------
__global__ __launch_bounds__(256) void gemm_feat(
    const float* __restrict__ hin, const float* __restrict__ Wm,
    const float* __restrict__ alv, const float* __restrict__ arv,
    float* __restrict__ feat, float* __restrict__ el, float* __restrict__ er)
{
    __shared__ float A[32][EMB + 1];
    const int tid  = threadIdx.x;
    const int base = blockIdx.x * 32;

    const float4* h4 = reinterpret_cast<const float4*>(hin);
    #pragma unroll
    for (int i = 0; i < 4; ++i) {
        int idx4 = tid + i * 256;
        int row  = idx4 >> 5;
        int c4   = idx4 & 31;
        float4 v = make_float4(0.f, 0.f, 0.f, 0.f);
        if (base + row < NND) v = h4[(size_t)(base + row) * 32 + c4];
        A[row][c4 * 4 + 0] = v.x;
        A[row][c4 * 4 + 1] = v.y;
        A[row][c4 * 4 + 2] = v.z;
        A[row][c4 * 4 + 3] = v.w;
    }
    __syncthreads();

    const int r  = tid >> 3;
    const int c8 = tid & 7;

    float acc[16];
    #pragma unroll
    for (int i = 0; i < 16; ++i) acc[i] = 0.f;

    const float4* W4 = reinterpret_cast<const float4*>(Wm) + c8 * 4;
    #pragma unroll 4
    for (int k = 0; k < 128; ++k) {
        float a = A[r][k];
        float4 w0 = W4[k * 32 + 0];
        float4 w1 = W4[k * 32 + 1];
        float4 w2 = W4[k * 32 + 2];
        float4 w3 = W4[k * 32 + 3];
        acc[0]  = fmaf(a, w0.x, acc[0]);  acc[1]  = fmaf(a, w0.y, acc[1]);
        acc[2]  = fmaf(a, w0.z, acc[2]);  acc[3]  = fmaf(a, w0.w, acc[3]);
        acc[4]  = fmaf(a, w1.x, acc[4]);  acc[5]  = fmaf(a, w1.y, acc[5]);
        acc[6]  = fmaf(a, w1.z, acc[6]);  acc[7]  = fmaf(a, w1.w, acc[7]);
        acc[8]  = fmaf(a, w2.x, acc[8]);  acc[9]  = fmaf(a, w2.y, acc[9]);
        acc[10] = fmaf(a, w2.z, acc[10]); acc[11] = fmaf(a, w2.w, acc[11]);
        acc[12] = fmaf(a, w3.x, acc[12]); acc[13] = fmaf(a, w3.y, acc[13]);
        acc[14] = fmaf(a, w3.z, acc[14]); acc[15] = fmaf(a, w3.w, acc[15]);
    }

    const int row = base + r;
    if (row < NND) {
        float4* f4 = reinterpret_cast<float4*>(feat + (size_t)row * EMB + c8 * 16);
        f4[0] = make_float4(acc[0],  acc[1],  acc[2],  acc[3]);
        f4[1] = make_float4(acc[4],  acc[5],  acc[6],  acc[7]);
        f4[2] = make_float4(acc[8],  acc[9],  acc[10], acc[11]);
        f4[3] = make_float4(acc[12], acc[13], acc[14], acc[15]);
        float sl = 0.f, sr = 0.f;
        #pragma unroll
        for (int i = 0; i < 16; ++i) {
            sl = fmaf(acc[i], alv[c8 * 16 + i], sl);
            sr = fmaf(acc[i], arv[c8 * 16 + i], sr);
        }
        el[row * NH + c8] = sl;
        er[row * NH + c8] = sr;
    }
}

// ---------------- CSR build (per path; reused across both layers) ----------------
__global__ __launch_bounds__(256) void deg_count(const int* __restrict__ dst, int* __restrict__ deg)
{
    int e = blockIdx.x * blockDim.x + threadIdx.x;
    if (e < NE) atomicAdd(&deg[dst[e]], 1);
}

// single-block exclusive scan of 50000 ints -> rowptr[N+1], cursor[N]
__global__ __launch_bounds__(1024) void scan_deg(const int* __restrict__ deg,
                                                 int* __restrict__ rowptr, int* __restrict__ cursor)
{
    __shared__ int ssum[1024];
    const int t  = threadIdx.x;
    const int CH = (NND + 1023) / 1024;  // 49
    const int base = t * CH;
    int s = 0;
    for (int j = 0; j < CH; ++j) {
        int idx = base + j;
        if (idx < NND) s += deg[idx];
    }
    ssum[t] = s;
    __syncthreads();
    for (int off = 1; off < 1024; off <<= 1) {
        int v = (t >= off) ? ssum[t - off] : 0;
        __syncthreads();
        ssum[t] += v;
        __syncthreads();
    }
    int run = (t > 0) ? ssum[t - 1] : 0;
    for (int j = 0; j < CH; ++j) {
        int idx = base + j;
        if (idx < NND) {
            rowptr[idx] = run;
            cursor[idx] = run;
            run += deg[idx];
        }
    }
    if (t == 1023) rowptr[NND] = run;
}

__global__ __launch_bounds__(256) void csr_fill(const int* __restrict__ src, const int* __restrict__ dst,
                                                int* __restrict__ cursor, int* __restrict__ csr_src)
{
    int e = blockIdx.x * blockDim.x + threadIdx.x;
    if (e >= NE) return;
    int p = atomicAdd(&cursor[dst[e]], 1);
    csr_src[p] = src[e];
}

// ---------------- Gather-aggregate: one wave per destination node ----------------
// lane l handles dims {2l, 2l+1}, head h = l/8. Fused: softmax-weighted sum,
// denominator, residual + bias + ELU. Writes esum for the alpha pass.
__global__ __launch_bounds__(256) void gather_agg(
    const int* __restrict__ rowptr, const int* __restrict__ csr_src,
    const float* __restrict__ el, const float* __restrict__ er,
    const float* __restrict__ feat, const float* __restrict__ hin,
    const float* __restrict__ bias, float* __restrict__ esum_out,
    float* __restrict__ hout)
{
    const int wid  = (blockIdx.x * blockDim.x + threadIdx.x) >> 6;  // node id
    const int lane = threadIdx.x & 63;
    if (wid >= NND) return;
    const int n = wid;
    const int h = lane >> 3;

    const float ern = er[n * NH + h];
    const float2* feat2 = reinterpret_cast<const float2*>(feat);

    float acc0 = 0.f, acc1 = 0.f, es = 0.f;
    const int r0 = rowptr[n], r1 = rowptr[n + 1];

    int i = r0;
    for (; i + 1 < r1; i += 2) {
        int s0 = csr_src[i];
        int s1 = csr_src[i + 1];
        float x0 = lrelu(el[s0 * NH + h] + ern);
        float x1 = lrelu(el[s1 * NH + h] + ern);
        float2 f0 = feat2[s0 * 64 + lane];
        float2 f1 = feat2[s1 * 64 + lane];
        float w0 = expf(x0), w1 = expf(x1);
        es += w0 + w1;
        acc0 = fmaf(w0, f0.x, acc0); acc1 = fmaf(w0, f0.y, acc1);
        acc0 = fmaf(w1, f1.x, acc0); acc1 = fmaf(w1, f1.y, acc1);
    }
    if (i < r1) {
        int s0 = csr_src[i];
        float x0 = lrelu(el[s0 * NH + h] + ern);
        float2 f0 = feat2[s0 * 64 + lane];
        float w0 = expf(x0);
        es += w0;
        acc0 = fmaf(w0, f0.x, acc0); acc1 = fmaf(w0, f0.y, acc1);
    }

    if ((lane & 7) == 0) esum_out[n * NH + h] = es;

    const float inv = 1.f / fmaxf(es, 1e-9f);
    float2 hv = reinterpret_cast<const float2*>(hin)[n * 64 + lane];
    float b0 = bias[lane * 2], b1 = bias[lane * 2 + 1];
    float2 o;
    o.x = elu(fmaf(acc0, inv, hv.x + b0));
    o.y = elu(fmaf(acc1, inv, hv.y + b1));
    reinterpret_cast<float2*>(hout)[n * 64 + lane] = o;
}

// ---------------- alpha in original edge order (last layer only) ----------------
__global__ __launch_bounds__(256) void alpha_write(
    const int* __restrict__ src, const int* __restrict__ dst,
    const float* __restrict__ el, const float* __restrict__ er,
    const float* __restrict__ esum, float* __restrict__ aout)
{
    int tid = blockIdx.x * blockDim.x + threadIdx.x;
    if (tid >= NE * NH) return;
    int e = tid >> 3;
    int h = tid & 7;
    int s = src[e], d = dst[e];
    float x = lrelu(el[s * NH + h] + er[d * NH + h]);
    float a = expf(x) / fmaxf(esum[d * NH + h], 1e-9f);
    aout[(size_t)e * NH + h] = a;
}

extern "C" void kernel_launch(void* const* d_in, const int* in_sizes, int n_in,
                              void* d_out, int out_size, void* d_ws, size_t ws_size,
                              hipStream_t stream) {
    const float* fs   = (const float*)d_in[0];  // [2][N][128]
    const float* W    = (const float*)d_in[1];  // [2][2][128][128]
    const float* al   = (const float*)d_in[2];  // [2][2][8][16]
    const float* ar   = (const float*)d_in[3];  // [2][2][8][16]
    const float* bias = (const float*)d_in[4];  // [2][2][128]
    const int*   edges= (const int*)d_in[5];    // [2][2][E]

    float* out       = (float*)d_out;
    float* out_emb   = out;                              // [2][N][128]
    float* out_alpha = out + (size_t)2 * NND * EMB;      // [2][E][8]

    char* ws = (char*)d_ws;
    float* feat   = (float*)ws;                       ws += (size_t)NND * EMB * 4;
    float* hbuf   = (float*)ws;                       ws += (size_t)NND * EMB * 4;
    float* el     = (float*)ws;                       ws += (size_t)NND * NH * 4;
    float* er     = (float*)ws;                       ws += (size_t)NND * NH * 4;
    float* esum   = (float*)ws;                       ws += (size_t)NND * NH * 4;
    int*   deg    = (int*)ws;                         ws += (size_t)NND * 4;
    int*   rowptr = (int*)ws;                         ws += (size_t)(NND + 1) * 4;
    int*   cursor = (int*)ws;                         ws += (size_t)NND * 4;
    int*   csrsrc = (int*)ws;                         ws += (size_t)NE * 4;

    for (int p = 0; p < 2; ++p) {
        const int* src = edges + (size_t)p * 2 * NE;
        const int* dst = src + NE;

        // Build CSR by dst once per path (edges identical for both layers).
        hipMemsetAsync(deg, 0, (size_t)NND * 4, stream);
        deg_count<<<(NE + 255) / 256, 256, 0, stream>>>(dst, deg);
        scan_deg<<<1, 1024, 0, stream>>>(deg, rowptr, cursor);
        csr_fill<<<(NE + 255) / 256, 256, 0, stream>>>(src, dst, cursor, csrsrc);

        for (int l = 0; l < 2; ++l) {
            const float* hin  = (l == 0) ? fs + (size_t)p * NND * EMB : hbuf;
            float*       hout = (l == 1) ? out_emb + (size_t)p * NND * EMB : hbuf;
            const float* Wl   = W    + (size_t)(p * 2 + l) * EMB * EMB;
            const float* alv  = al   + (size_t)(p * 2 + l) * NH * HD;
            const float* arv  = ar   + (size_t)(p * 2 + l) * NH * HD;
            const float* bl   = bias + (size_t)(p * 2 + l) * EMB;

            gemm_feat<<<(NND + 31) / 32, 256, 0, stream>>>(hin, Wl, alv, arv, feat, el, er);
            gather_agg<<<(NND + 3) / 4, 256, 0, stream>>>(rowptr, csrsrc, el, er, feat, hin, bl, esum, hout);
            if (l == 1) {
                alpha_write<<<((size_t)NE * NH + 255) / 256, 256, 0, stream>>>(
                    src, dst, el, er, esum, out_alpha + (size_t)p * NE * NH);
            }
        }
    }
}

// Round 3
// 1415.809 us; speedup vs baseline: 34.8686x; 1.4699x over previous
//
#include <hip/hip_runtime.h>
#include <hip/hip_bf16.h>

#define NND 50000
#define NE  1600000
#define EMB 128
#define NH  8
#define HD  16

typedef __attribute__((ext_vector_type(8))) short short8v;
typedef __attribute__((ext_vector_type(4))) float f32x4;

__device__ __forceinline__ float lrelu(float x) { return x > 0.f ? x : 0.2f * x; }
__device__ __forceinline__ float elu(float x)   { return x > 0.f ? x : expm1f(x); }

__device__ __forceinline__ unsigned short f2bf(float x) {
    __hip_bfloat16 b = __float2bfloat16(x);
    return *reinterpret_cast<unsigned short*>(&b);
}
__device__ __forceinline__ float bf2f(unsigned short u) {
    __hip_bfloat16 b = *reinterpret_cast<__hip_bfloat16*>(&u);
    return __bfloat162float(b);
}

// ---------------- split h into bf16 hi/lo (x = hi + lo + eps) ----------------
__global__ __launch_bounds__(256) void hsplit(
    const float* __restrict__ hin, unsigned short* __restrict__ hhi, unsigned short* __restrict__ hlo)
{
    int idx = blockIdx.x * 256 + threadIdx.x;   // each handles 8 floats; grid exact
    const float4* h4 = reinterpret_cast<const float4*>(hin);
    float4 v0 = h4[(size_t)idx * 2];
    float4 v1 = h4[(size_t)idx * 2 + 1];
    float xs[8] = { v0.x, v0.y, v0.z, v0.w, v1.x, v1.y, v1.z, v1.w };
    unsigned short hi[8], lo[8];
    #pragma unroll
    for (int j = 0; j < 8; ++j) {
        hi[j] = f2bf(xs[j]);
        lo[j] = f2bf(xs[j] - bf2f(hi[j]));
    }
    *reinterpret_cast<uint4*>(hhi + (size_t)idx * 8) = *reinterpret_cast<uint4*>(hi);
    *reinterpret_cast<uint4*>(hlo + (size_t)idx * 8) = *reinterpret_cast<uint4*>(lo);
}

// ---------------- pack W into per-fragment bf16 hi/lo layout ----------------
// bp[(n*4+kt)*64+lane][j] = W[kt*32 + (lane>>4)*8 + j][n*16 + (lane&15)]
__global__ __launch_bounds__(256) void wpack(
    const float* __restrict__ Wm, unsigned short* __restrict__ bphi, unsigned short* __restrict__ bplo)
{
    for (int s = threadIdx.x; s < 2048; s += 256) {
        int n    = s >> 8;
        int kt   = (s >> 6) & 3;
        int lane = s & 63;
        int col  = n * 16 + (lane & 15);
        int krow = kt * 32 + ((lane >> 4) << 3);
        #pragma unroll
        for (int j = 0; j < 8; ++j) {
            float x = Wm[(size_t)(krow + j) * EMB + col];
            unsigned short hi = f2bf(x);
            unsigned short lo = f2bf(x - bf2f(hi));
            bphi[(size_t)s * 8 + j] = hi;
            bplo[(size_t)s * 8 + j] = lo;
        }
    }
}

// ---------------- MFMA GEMM: feat = h @ W (bf16x3), fused el/er ----------------
// Block 256 = 4 waves; wave handles 32 rows x 128 cols; 16x16x32 bf16 MFMA.
__global__ __launch_bounds__(256) void mfma_gemm(
    const unsigned short* __restrict__ hhi, const unsigned short* __restrict__ hlo,
    const unsigned short* __restrict__ bphi, const unsigned short* __restrict__ bplo,
    const float* __restrict__ alv, const float* __restrict__ arv,
    float* __restrict__ feat, float* __restrict__ el, float* __restrict__ er)
{
    const int lane = threadIdx.x & 63;
    const int wave = threadIdx.x >> 6;
    const int rowbase = blockIdx.x * 128 + wave * 32;

    f32x4 acc[2][8];
    #pragma unroll
    for (int m = 0; m < 2; ++m)
        #pragma unroll
        for (int n = 0; n < 8; ++n)
            acc[m][n] = (f32x4){0.f, 0.f, 0.f, 0.f};

    const int ar0 = rowbase + (lane & 15);
    const int ar1 = ar0 + 16;
    const int car0 = ar0 < NND ? ar0 : NND - 1;
    const int car1 = ar1 < NND ? ar1 : NND - 1;
    const int kofs = (lane >> 4) * 8;

    #pragma unroll
    for (int kt = 0; kt < 4; ++kt) {
        const int k0 = kt * 32 + kofs;
        short8v ah0 = *reinterpret_cast<const short8v*>(hhi + (size_t)car0 * EMB + k0);
        short8v ah1 = *reinterpret_cast<const short8v*>(hhi + (size_t)car1 * EMB + k0);
        short8v al0 = *reinterpret_cast<const short8v*>(hlo + (size_t)car0 * EMB + k0);
        short8v al1 = *reinterpret_cast<const short8v*>(hlo + (size_t)car1 * EMB + k0);
        #pragma unroll
        for (int n = 0; n < 8; ++n) {
            const size_t bofs = ((size_t)(n * 4 + kt) * 64 + lane) * 8;
            short8v bh = *reinterpret_cast<const short8v*>(bphi + bofs);
            short8v bl = *reinterpret_cast<const short8v*>(bplo + bofs);
            acc[0][n] = __builtin_amdgcn_mfma_f32_16x16x32_bf16(ah0, bh, acc[0][n], 0, 0, 0);
            acc[1][n] = __builtin_amdgcn_mfma_f32_16x16x32_bf16(ah1, bh, acc[1][n], 0, 0, 0);
            acc[0][n] = __builtin_amdgcn_mfma_f32_16x16x32_bf16(al0, bh, acc[0][n], 0, 0, 0);
            acc[1][n] = __builtin_amdgcn_mfma_f32_16x16x32_bf16(al1, bh, acc[1][n], 0, 0, 0);
            acc[0][n] = __builtin_amdgcn_mfma_f32_16x16x32_bf16(ah0, bl, acc[0][n], 0, 0, 0);
            acc[1][n] = __builtin_amdgcn_mfma_f32_16x16x32_bf16(ah1, bl, acc[1][n], 0, 0, 0);
        }
    }

    // epilogue: feat stores + el/er (head h == n-tile) via 16-lane xor reduce
    const int colr = lane & 15;
    const int rgrp = lane >> 4;
    #pragma unroll
    for (int n = 0; n < 8; ++n) {
        const float alc = alv[n * 16 + colr];
        const float arc = arv[n * 16 + colr];
        #pragma unroll
        for (int m = 0; m < 2; ++m) {
            f32x4 a = acc[m][n];
            const int row0 = rowbase + m * 16 + rgrp * 4;
            #pragma unroll
            for (int r = 0; r < 4; ++r) {
                if (row0 + r < NND)
                    feat[(size_t)(row0 + r) * EMB + n * 16 + colr] = a[r];
            }
            float pl[4], pr[4];
            #pragma unroll
            for (int r = 0; r < 4; ++r) { pl[r] = a[r] * alc; pr[r] = a[r] * arc; }
            #pragma unroll
            for (int mask = 1; mask < 16; mask <<= 1) {
                #pragma unroll
                for (int r = 0; r < 4; ++r) {
                    pl[r] += __shfl_xor(pl[r], mask);
                    pr[r] += __shfl_xor(pr[r], mask);
                }
            }
            if (colr == 0) {
                #pragma unroll
                for (int r = 0; r < 4; ++r) {
                    int row = row0 + r;
                    if (row < NND) {
                        el[row * NH + n] = pl[r];
                        er[row * NH + n] = pr[r];
                    }
                }
            }
        }
    }
}

// ---------------- CSR build (per path; reused across both layers) ----------------
__global__ __launch_bounds__(256) void deg_count(const int* __restrict__ dst, int* __restrict__ deg)
{
    int e = blockIdx.x * blockDim.x + threadIdx.x;
    if (e < NE) atomicAdd(&deg[dst[e]], 1);
}

__global__ __launch_bounds__(1024) void scan_deg(const int* __restrict__ deg,
                                                 int* __restrict__ rowptr, int* __restrict__ cursor)
{
    __shared__ int ssum[1024];
    const int t  = threadIdx.x;
    const int CH = (NND + 1023) / 1024;
    const int base = t * CH;
    int s = 0;
    for (int j = 0; j < CH; ++j) {
        int idx = base + j;
        if (idx < NND) s += deg[idx];
    }
    ssum[t] = s;
    __syncthreads();
    for (int off = 1; off < 1024; off <<= 1) {
        int v = (t >= off) ? ssum[t - off] : 0;
        __syncthreads();
        ssum[t] += v;
        __syncthreads();
    }
    int run = (t > 0) ? ssum[t - 1] : 0;
    for (int j = 0; j < CH; ++j) {
        int idx = base + j;
        if (idx < NND) {
            rowptr[idx] = run;
            cursor[idx] = run;
            run += deg[idx];
        }
    }
    if (t == 1023) rowptr[NND] = run;
}

__global__ __launch_bounds__(256) void csr_fill(const int* __restrict__ src, const int* __restrict__ dst,
                                                int* __restrict__ cursor, int* __restrict__ csr_src)
{
    int e = blockIdx.x * blockDim.x + threadIdx.x;
    if (e >= NE) return;
    int p = atomicAdd(&cursor[dst[e]], 1);
    csr_src[p] = src[e];
}

// ---------------- Gather-aggregate: one wave per destination node ----------------
__global__ __launch_bounds__(256) void gather_agg(
    const int* __restrict__ rowptr, const int* __restrict__ csr_src,
    const float* __restrict__ el, const float* __restrict__ er,
    const float* __restrict__ feat, const float* __restrict__ hin,
    const float* __restrict__ bias, float* __restrict__ esum_out,
    float* __restrict__ hout)
{
    const int wid  = (blockIdx.x * blockDim.x + threadIdx.x) >> 6;
    const int lane = threadIdx.x & 63;
    if (wid >= NND) return;
    const int n = wid;
    const int h = lane >> 3;

    const float ern = er[n * NH + h];
    const float2* feat2 = reinterpret_cast<const float2*>(feat);

    float acc0 = 0.f, acc1 = 0.f, es = 0.f;
    const int r0 = rowptr[n], r1 = rowptr[n + 1];

    int i = r0;
    for (; i + 1 < r1; i += 2) {
        int s0 = csr_src[i];
        int s1 = csr_src[i + 1];
        float x0 = lrelu(el[s0 * NH + h] + ern);
        float x1 = lrelu(el[s1 * NH + h] + ern);
        float2 f0 = feat2[s0 * 64 + lane];
        float2 f1 = feat2[s1 * 64 + lane];
        float w0 = expf(x0), w1 = expf(x1);
        es += w0 + w1;
        acc0 = fmaf(w0, f0.x, acc0); acc1 = fmaf(w0, f0.y, acc1);
        acc0 = fmaf(w1, f1.x, acc0); acc1 = fmaf(w1, f1.y, acc1);
    }
    if (i < r1) {
        int s0 = csr_src[i];
        float x0 = lrelu(el[s0 * NH + h] + ern);
        float2 f0 = feat2[s0 * 64 + lane];
        float w0 = expf(x0);
        es += w0;
        acc0 = fmaf(w0, f0.x, acc0); acc1 = fmaf(w0, f0.y, acc1);
    }

    if ((lane & 7) == 0) esum_out[n * NH + h] = es;

    const float inv = 1.f / fmaxf(es, 1e-9f);
    float2 hv = reinterpret_cast<const float2*>(hin)[n * 64 + lane];
    float b0 = bias[lane * 2], b1 = bias[lane * 2 + 1];
    float2 o;
    o.x = elu(fmaf(acc0, inv, hv.x + b0));
    o.y = elu(fmaf(acc1, inv, hv.y + b1));
    reinterpret_cast<float2*>(hout)[n * 64 + lane] = o;
}

// ---------------- alpha in original edge order (last layer only) ----------------
__global__ __launch_bounds__(256) void alpha_write(
    const int* __restrict__ src, const int* __restrict__ dst,
    const float* __restrict__ el, const float* __restrict__ er,
    const float* __restrict__ esum, float* __restrict__ aout)
{
    int tid = blockIdx.x * blockDim.x + threadIdx.x;
    if (tid >= NE * NH) return;
    int e = tid >> 3;
    int h = tid & 7;
    int s = src[e], d = dst[e];
    float x = lrelu(el[s * NH + h] + er[d * NH + h]);
    float a = expf(x) / fmaxf(esum[d * NH + h], 1e-9f);
    aout[(size_t)e * NH + h] = a;
}

extern "C" void kernel_launch(void* const* d_in, const int* in_sizes, int n_in,
                              void* d_out, int out_size, void* d_ws, size_t ws_size,
                              hipStream_t stream) {
    const float* fs   = (const float*)d_in[0];  // [2][N][128]
    const float* W    = (const float*)d_in[1];  // [2][2][128][128]
    const float* al   = (const float*)d_in[2];  // [2][2][8][16]
    const float* ar   = (const float*)d_in[3];  // [2][2][8][16]
    const float* bias = (const float*)d_in[4];  // [2][2][128]
    const int*   edges= (const int*)d_in[5];    // [2][2][E]

    float* out       = (float*)d_out;
    float* out_emb   = out;                              // [2][N][128]
    float* out_alpha = out + (size_t)2 * NND * EMB;      // [2][E][8]

    char* ws = (char*)d_ws;
    float*          feat   = (float*)ws;          ws += (size_t)NND * EMB * 4;
    float*          hbuf   = (float*)ws;          ws += (size_t)NND * EMB * 4;
    float*          el     = (float*)ws;          ws += (size_t)NND * NH * 4;
    float*          er     = (float*)ws;          ws += (size_t)NND * NH * 4;
    float*          esum   = (float*)ws;          ws += (size_t)NND * NH * 4;
    int*            deg    = (int*)ws;            ws += (size_t)NND * 4;
    int*            rowptr = (int*)ws;            ws += (size_t)(NND + 1) * 4;
    int*            cursor = (int*)ws;            ws += (size_t)NND * 4;
    int*            csrsrc = (int*)ws;            ws += (size_t)NE * 4;
    unsigned short* hhi    = (unsigned short*)ws; ws += (size_t)NND * EMB * 2;
    unsigned short* hlo    = (unsigned short*)ws; ws += (size_t)NND * EMB * 2;
    unsigned short* bphi   = (unsigned short*)ws; ws += (size_t)16384 * 2;
    unsigned short* bplo   = (unsigned short*)ws; ws += (size_t)16384 * 2;

    for (int p = 0; p < 2; ++p) {
        const int* src = edges + (size_t)p * 2 * NE;
        const int* dst = src + NE;

        hipMemsetAsync(deg, 0, (size_t)NND * 4, stream);
        deg_count<<<(NE + 255) / 256, 256, 0, stream>>>(dst, deg);
        scan_deg<<<1, 1024, 0, stream>>>(deg, rowptr, cursor);
        csr_fill<<<(NE + 255) / 256, 256, 0, stream>>>(src, dst, cursor, csrsrc);

        for (int l = 0; l < 2; ++l) {
            const float* hin  = (l == 0) ? fs + (size_t)p * NND * EMB : hbuf;
            float*       hout = (l == 1) ? out_emb + (size_t)p * NND * EMB : hbuf;
            const float* Wl   = W    + (size_t)(p * 2 + l) * EMB * EMB;
            const float* alv  = al   + (size_t)(p * 2 + l) * NH * HD;
            const float* arv  = ar   + (size_t)(p * 2 + l) * NH * HD;
            const float* bl   = bias + (size_t)(p * 2 + l) * EMB;

            wpack<<<1, 256, 0, stream>>>(Wl, bphi, bplo);
            hsplit<<<(NND * EMB / 8 + 255) / 256, 256, 0, stream>>>(hin, hhi, hlo);
            mfma_gemm<<<(NND + 127) / 128, 256, 0, stream>>>(hhi, hlo, bphi, bplo, alv, arv, feat, el, er);
            gather_agg<<<(NND + 3) / 4, 256, 0, stream>>>(rowptr, csrsrc, el, er, feat, hin, bl, esum, hout);
            if (l == 1) {
                alpha_write<<<((size_t)NE * NH + 255) / 256, 256, 0, stream>>>(
                    src, dst, el, er, esum, out_alpha + (size_t)p * NE * NH);
            }
        }
    }
}

// Round 5
// 1333.209 us; speedup vs baseline: 37.0289x; 1.0620x over previous
//
#include <hip/hip_runtime.h>
#include <hip/hip_bf16.h>

#define NND 50000
#define NE  1600000
#define EMB 128
#define NH  8
#define HD  16

typedef __attribute__((ext_vector_type(8))) short short8v;
typedef __attribute__((ext_vector_type(4))) float f32x4;

__device__ __forceinline__ float lrelu(float x) { return x > 0.f ? x : 0.2f * x; }
__device__ __forceinline__ float elu(float x)   { return x > 0.f ? x : expm1f(x); }

__device__ __forceinline__ unsigned short f2bf(float x) {
    __hip_bfloat16 b = __float2bfloat16(x);
    return *reinterpret_cast<unsigned short*>(&b);
}
__device__ __forceinline__ float bf2f(unsigned short u) {
    __hip_bfloat16 b = *reinterpret_cast<__hip_bfloat16*>(&u);
    return __bfloat162float(b);
}

// ---------------- split h into bf16 hi/lo (x ~= hi + lo) ----------------
__global__ __launch_bounds__(256) void hsplit(
    const float* __restrict__ hin, unsigned short* __restrict__ hhi, unsigned short* __restrict__ hlo)
{
    int idx = blockIdx.x * 256 + threadIdx.x;   // each handles 8 floats; grid exact
    const float4* h4 = reinterpret_cast<const float4*>(hin);
    float4 v0 = h4[(size_t)idx * 2];
    float4 v1 = h4[(size_t)idx * 2 + 1];
    float xs[8] = { v0.x, v0.y, v0.z, v0.w, v1.x, v1.y, v1.z, v1.w };
    unsigned short hi[8], lo[8];
    #pragma unroll
    for (int j = 0; j < 8; ++j) {
        hi[j] = f2bf(xs[j]);
        lo[j] = f2bf(xs[j] - bf2f(hi[j]));
    }
    *reinterpret_cast<uint4*>(hhi + (size_t)idx * 8) = *reinterpret_cast<uint4*>(hi);
    *reinterpret_cast<uint4*>(hlo + (size_t)idx * 8) = *reinterpret_cast<uint4*>(lo);
}

// ---------------- pack W into per-fragment bf16 hi/lo layout ----------------
// bp[(n*4+kt)*64+lane][j] = W[kt*32 + (lane>>4)*8 + j][n*16 + (lane&15)]
__global__ __launch_bounds__(256) void wpack(
    const float* __restrict__ Wm, unsigned short* __restrict__ bphi, unsigned short* __restrict__ bplo)
{
    int s = blockIdx.x * 256 + threadIdx.x;   // grid 8 x 256 = 2048
    if (s >= 2048) return;
    int n    = s >> 8;
    int kt   = (s >> 6) & 3;
    int lane = s & 63;
    int col  = n * 16 + (lane & 15);
    int krow = kt * 32 + ((lane >> 4) << 3);
    #pragma unroll
    for (int j = 0; j < 8; ++j) {
        float x = Wm[(size_t)(krow + j) * EMB + col];
        unsigned short hi = f2bf(x);
        unsigned short lo = f2bf(x - bf2f(hi));
        bphi[(size_t)s * 8 + j] = hi;
        bplo[(size_t)s * 8 + j] = lo;
    }
}

// ---------------- MFMA GEMM: feat = h @ W (bf16x3), fused el/er ----------------
// Block 256 = 4 waves; wave handles 16 rows x 128 cols; 16x16x32 bf16 MFMA.
__global__ __launch_bounds__(256) void mfma_gemm(
    const unsigned short* __restrict__ hhi, const unsigned short* __restrict__ hlo,
    const unsigned short* __restrict__ bphi, const unsigned short* __restrict__ bplo,
    const float* __restrict__ alv, const float* __restrict__ arv,
    unsigned short* __restrict__ feat_bf, float* __restrict__ el, float* __restrict__ er)
{
    const int lane = threadIdx.x & 63;
    const int wave = threadIdx.x >> 6;
    const int rowbase = blockIdx.x * 64 + wave * 16;

    f32x4 acc[8];
    #pragma unroll
    for (int nn = 0; nn < 8; ++nn) acc[nn] = (f32x4){0.f, 0.f, 0.f, 0.f};

    const int ar  = rowbase + (lane & 15);
    const int car = ar < NND ? ar : NND - 1;
    const int kofs = (lane >> 4) * 8;

    #pragma unroll
    for (int kt = 0; kt < 4; ++kt) {
        const int k0 = kt * 32 + kofs;
        short8v ah = *reinterpret_cast<const short8v*>(hhi + (size_t)car * EMB + k0);
        short8v av = *reinterpret_cast<const short8v*>(hlo + (size_t)car * EMB + k0);
        #pragma unroll
        for (int nn = 0; nn < 8; ++nn) {
            const size_t bofs = ((size_t)(nn * 4 + kt) * 64 + lane) * 8;
            short8v bh = *reinterpret_cast<const short8v*>(bphi + bofs);
            short8v bl = *reinterpret_cast<const short8v*>(bplo + bofs);
            acc[nn] = __builtin_amdgcn_mfma_f32_16x16x32_bf16(ah, bh, acc[nn], 0, 0, 0);
            acc[nn] = __builtin_amdgcn_mfma_f32_16x16x32_bf16(av, bh, acc[nn], 0, 0, 0);
            acc[nn] = __builtin_amdgcn_mfma_f32_16x16x32_bf16(ah, bl, acc[nn], 0, 0, 0);
        }
    }

    const int colr = lane & 15;
    const int rgrp = lane >> 4;
    const int row0 = rowbase + rgrp * 4;
    #pragma unroll
    for (int nn = 0; nn < 8; ++nn) {
        f32x4 a = acc[nn];
        #pragma unroll
        for (int r = 0; r < 4; ++r) {
            if (row0 + r < NND)
                feat_bf[(size_t)(row0 + r) * EMB + nn * 16 + colr] = f2bf(a[r]);
        }
        const float alc = alv[nn * 16 + colr];
        const float arc = arv[nn * 16 + colr];
        float pl[4], pr[4];
        #pragma unroll
        for (int r = 0; r < 4; ++r) { pl[r] = a[r] * alc; pr[r] = a[r] * arc; }
        #pragma unroll
        for (int mask = 1; mask < 16; mask <<= 1) {
            #pragma unroll
            for (int r = 0; r < 4; ++r) {
                pl[r] += __shfl_xor(pl[r], mask);
                pr[r] += __shfl_xor(pr[r], mask);
            }
        }
        if (colr == 0) {
            #pragma unroll
            for (int r = 0; r < 4; ++r) {
                int row = row0 + r;
                if (row < NND) {
                    el[row * NH + nn] = pl[r];
                    er[row * NH + nn] = pr[r];
                }
            }
        }
    }
}

// ---------------- CSR build (per path; reused across both layers) ----------------
__global__ __launch_bounds__(256) void deg_count(const int* __restrict__ dst, int* __restrict__ deg)
{
    int e = blockIdx.x * blockDim.x + threadIdx.x;
    if (e < NE) atomicAdd(&deg[dst[e]], 1);
}

__global__ __launch_bounds__(1024) void scan_deg(const int* __restrict__ deg,
                                                 int* __restrict__ rowptr, int* __restrict__ cursor)
{
    __shared__ int ssum[1024];
    const int t  = threadIdx.x;
    const int CH = (NND + 1023) / 1024;
    const int base = t * CH;
    int s = 0;
    for (int j = 0; j < CH; ++j) {
        int idx = base + j;
        if (idx < NND) s += deg[idx];
    }
    ssum[t] = s;
    __syncthreads();
    for (int off = 1; off < 1024; off <<= 1) {
        int v = (t >= off) ? ssum[t - off] : 0;
        __syncthreads();
        ssum[t] += v;
        __syncthreads();
    }
    int run = (t > 0) ? ssum[t - 1] : 0;
    for (int j = 0; j < CH; ++j) {
        int idx = base + j;
        if (idx < NND) {
            rowptr[idx] = run;
            cursor[idx] = run;
            run += deg[idx];
        }
    }
    if (t == 1023) rowptr[NND] = run;
}

__global__ __launch_bounds__(256) void csr_fill(const int* __restrict__ src, const int* __restrict__ dst,
                                                int* __restrict__ cursor, int* __restrict__ csr_src)
{
    int e = blockIdx.x * blockDim.x + threadIdx.x;
    if (e >= NE) return;
    int p = atomicAdd(&cursor[dst[e]], 1);
    csr_src[p] = src[e];
}

// ---------------- Gather-aggregate: one wave per destination node ----------------
// Chunk-of-8 shared-exp: lane (j=l&7, h=l>>3) computes one distinct exp weight,
// phase 2 broadcasts via shfl. feat read as bf16 pairs. Fused residual+bias+ELU;
// layer-1 emits the bf16 hi/lo split for next layer's GEMM, layer-2 emits f32 out.
__global__ __launch_bounds__(256) void gather_agg(
    const int* __restrict__ rowptr, const int* __restrict__ csrsrc,
    const float* __restrict__ el, const float* __restrict__ er,
    const unsigned int* __restrict__ featu,
    const float* __restrict__ hin_f32,          // layer1 residual (fs) or null
    const unsigned int* __restrict__ hin_hi,    // layer2 residual (hi/lo) or null
    const unsigned int* __restrict__ hin_lo,
    const float* __restrict__ bias,
    float* __restrict__ esum_out,
    float* __restrict__ hout_f32,               // layer2 out or null
    unsigned int* __restrict__ hhi_out,         // layer1 out or null
    unsigned int* __restrict__ hlo_out)
{
    const int wid  = (blockIdx.x * blockDim.x + threadIdx.x) >> 6;
    const int lane = threadIdx.x & 63;
    if (wid >= NND) return;
    const int n  = wid;
    const int h  = lane >> 3;   // head (softmax + feat dims)
    const int j8 = lane & 7;    // edge slot in chunk

    const float ern = er[n * NH + h];
    const int r0 = __builtin_amdgcn_readfirstlane(rowptr[n]);
    const int r1 = __builtin_amdgcn_readfirstlane(rowptr[n + 1]);

    float acc0 = 0.f, acc1 = 0.f, es = 0.f;

    for (int i = r0; i < r1; i += 8) {
        const int m = r1 - i;                              // wave-uniform
        int idx = i + j8;
        int sv  = csrsrc[idx < r1 ? idx : (r1 - 1)];
        float w = 0.f;
        if (j8 < m) w = expf(lrelu(el[sv * NH + h] + ern));
        #pragma unroll
        for (int j = 0; j < 8; ++j) {
            if (j >= m) break;                             // uniform
            int   sj = __shfl(sv, j);
            float wj = __shfl(w, (lane & 56) | j);
            unsigned int v = featu[(size_t)sj * 64 + lane];
            float f0 = __uint_as_float(v << 16);
            float f1 = __uint_as_float(v & 0xffff0000u);
            es  += wj;
            acc0 = fmaf(wj, f0, acc0);
            acc1 = fmaf(wj, f1, acc1);
        }
    }

    if (j8 == 0) esum_out[n * NH + h] = es;
    const float inv = 1.f / fmaxf(es, 1e-9f);

    float h0, h1;
    if (hin_f32) {
        float2 hv = reinterpret_cast<const float2*>(hin_f32)[(size_t)n * 64 + lane];
        h0 = hv.x; h1 = hv.y;
    } else {
        unsigned int hiu = hin_hi[(size_t)n * 64 + lane];
        unsigned int lou = hin_lo[(size_t)n * 64 + lane];
        h0 = __uint_as_float(hiu << 16) + __uint_as_float(lou << 16);
        h1 = __uint_as_float(hiu & 0xffff0000u) + __uint_as_float(lou & 0xffff0000u);
    }
    float o0 = elu(fmaf(acc0, inv, h0 + bias[lane * 2]));
    float o1 = elu(fmaf(acc1, inv, h1 + bias[lane * 2 + 1]));

    if (hout_f32) {
        reinterpret_cast<float2*>(hout_f32)[(size_t)n * 64 + lane] = make_float2(o0, o1);
    } else {
        unsigned short hi0 = f2bf(o0), hi1 = f2bf(o1);
        unsigned short lo0 = f2bf(o0 - bf2f(hi0)), lo1 = f2bf(o1 - bf2f(hi1));
        hhi_out[(size_t)n * 64 + lane] = (unsigned int)hi0 | ((unsigned int)hi1 << 16);
        hlo_out[(size_t)n * 64 + lane] = (unsigned int)lo0 | ((unsigned int)lo1 << 16);
    }
}

// ---------------- alpha in original edge order (last layer only) ----------------
__global__ __launch_bounds__(256) void alpha_write(
    const int* __restrict__ src, const int* __restrict__ dst,
    const float* __restrict__ el, const float* __restrict__ er,
    const float* __restrict__ esum, float* __restrict__ aout)
{
    int tid = blockIdx.x * blockDim.x + threadIdx.x;
    if (tid >= NE * NH) return;
    int e = tid >> 3;
    int h = tid & 7;
    int s = src[e], d = dst[e];
    float x = lrelu(el[s * NH + h] + er[d * NH + h]);
    float a = expf(x) / fmaxf(esum[d * NH + h], 1e-9f);
    aout[(size_t)e * NH + h] = a;
}

extern "C" void kernel_launch(void* const* d_in, const int* in_sizes, int n_in,
                              void* d_out, int out_size, void* d_ws, size_t ws_size,
                              hipStream_t stream) {
    const float* fs   = (const float*)d_in[0];  // [2][N][128]
    const float* W    = (const float*)d_in[1];  // [2][2][128][128]
    const float* al   = (const float*)d_in[2];  // [2][2][8][16]
    const float* ar   = (const float*)d_in[3];  // [2][2][8][16]
    const float* bias = (const float*)d_in[4];  // [2][2][128]
    const int*   edges= (const int*)d_in[5];    // [2][2][E]

    float* out       = (float*)d_out;
    float* out_emb   = out;                              // [2][N][128]
    float* out_alpha = out + (size_t)2 * NND * EMB;      // [2][E][8]

    char* ws = (char*)d_ws;
    unsigned short* feat_bf = (unsigned short*)ws; ws += (size_t)NND * EMB * 2;
    unsigned short* hhi     = (unsigned short*)ws; ws += (size_t)NND * EMB * 2;
    unsigned short* hlo     = (unsigned short*)ws; ws += (size_t)NND * EMB * 2;
    float*          el      = (float*)ws;          ws += (size_t)NND * NH * 4;
    float*          er      = (float*)ws;          ws += (size_t)NND * NH * 4;
    float*          esum    = (float*)ws;          ws += (size_t)NND * NH * 4;
    int*            deg     = (int*)ws;            ws += (size_t)NND * 4;
    int*            rowptr  = (int*)ws;            ws += (size_t)(NND + 1) * 4;
    int*            cursor  = (int*)ws;            ws += (size_t)NND * 4;
    int*            csrsrc  = (int*)ws;            ws += (size_t)NE * 4;
    unsigned short* bphi    = (unsigned short*)ws; ws += (size_t)16384 * 2;
    unsigned short* bplo    = (unsigned short*)ws; ws += (size_t)16384 * 2;

    unsigned int* featu = (unsigned int*)feat_bf;
    unsigned int* hhi_u = (unsigned int*)hhi;
    unsigned int* hlo_u = (unsigned int*)hlo;

    for (int p = 0; p < 2; ++p) {
        const int* src = edges + (size_t)p * 2 * NE;
        const int* dst = src + NE;

        hipMemsetAsync(deg, 0, (size_t)NND * 4, stream);
        deg_count<<<(NE + 255) / 256, 256, 0, stream>>>(dst, deg);
        scan_deg<<<1, 1024, 0, stream>>>(deg, rowptr, cursor);
        csr_fill<<<(NE + 255) / 256, 256, 0, stream>>>(src, dst, cursor, csrsrc);

        for (int l = 0; l < 2; ++l) {
            const float* fsp  = fs + (size_t)p * NND * EMB;
            const float* Wl   = W    + (size_t)(p * 2 + l) * EMB * EMB;
            const float* alv  = al   + (size_t)(p * 2 + l) * NH * HD;
            const float* arv  = ar   + (size_t)(p * 2 + l) * NH * HD;
            const float* bl   = bias + (size_t)(p * 2 + l) * EMB;

            wpack<<<8, 256, 0, stream>>>(Wl, bphi, bplo);
            if (l == 0)
                hsplit<<<NND * EMB / 8 / 256, 256, 0, stream>>>(fsp, hhi, hlo);

            mfma_gemm<<<(NND + 63) / 64, 256, 0, stream>>>(hhi, hlo, bphi, bplo, alv, arv, feat_bf, el, er);

            if (l == 0) {
                gather_agg<<<(NND + 3) / 4, 256, 0, stream>>>(
                    rowptr, csrsrc, el, er, featu,
                    fsp, nullptr, nullptr, bl, esum,
                    nullptr, hhi_u, hlo_u);
            } else {
                gather_agg<<<(NND + 3) / 4, 256, 0, stream>>>(
                    rowptr, csrsrc, el, er, featu,
                    nullptr, hhi_u, hlo_u, bl, esum,
                    out_emb + (size_t)p * NND * EMB, nullptr, nullptr);
                alpha_write<<<((size_t)NE * NH + 255) / 256, 256, 0, stream>>>(
                    src, dst, el, er, esum, out_alpha + (size_t)p * NE * NH);
            }
        }
    }
}

// Round 6
// 1145.606 us; speedup vs baseline: 43.0927x; 1.1638x over previous
//
#include <hip/hip_runtime.h>
#include <hip/hip_bf16.h>

#define NND 50000
#define NE  1600000
#define EMB 128
#define NH  8
#define HD  16
#define NB  98            // ceil(50000/512) buckets of 512 dst nodes

typedef __attribute__((ext_vector_type(8))) short short8v;
typedef __attribute__((ext_vector_type(4))) float f32x4;

__device__ __forceinline__ float lrelu(float x) { return x > 0.f ? x : 0.2f * x; }
__device__ __forceinline__ float elu(float x)   { return x > 0.f ? x : expm1f(x); }

__device__ __forceinline__ unsigned short f2bf(float x) {
    __hip_bfloat16 b = __float2bfloat16(x);
    return *reinterpret_cast<unsigned short*>(&b);
}
__device__ __forceinline__ float bf2f(unsigned short u) {
    __hip_bfloat16 b = *reinterpret_cast<__hip_bfloat16*>(&u);
    return __bfloat162float(b);
}

// ---------------- split h into bf16 hi/lo (x ~= hi + lo) ----------------
__global__ __launch_bounds__(256) void hsplit(
    const float* __restrict__ hin, unsigned short* __restrict__ hhi, unsigned short* __restrict__ hlo)
{
    int idx = blockIdx.x * 256 + threadIdx.x;   // each handles 8 floats; grid exact
    const float4* h4 = reinterpret_cast<const float4*>(hin);
    float4 v0 = h4[(size_t)idx * 2];
    float4 v1 = h4[(size_t)idx * 2 + 1];
    float xs[8] = { v0.x, v0.y, v0.z, v0.w, v1.x, v1.y, v1.z, v1.w };
    unsigned short hi[8], lo[8];
    #pragma unroll
    for (int j = 0; j < 8; ++j) {
        hi[j] = f2bf(xs[j]);
        lo[j] = f2bf(xs[j] - bf2f(hi[j]));
    }
    *reinterpret_cast<uint4*>(hhi + (size_t)idx * 8) = *reinterpret_cast<uint4*>(hi);
    *reinterpret_cast<uint4*>(hlo + (size_t)idx * 8) = *reinterpret_cast<uint4*>(lo);
}

// ---------------- pack W into per-fragment bf16 hi/lo layout ----------------
// bp[(n*4+kt)*64+lane][j] = W[kt*32 + (lane>>4)*8 + j][n*16 + (lane&15)]
__global__ __launch_bounds__(256) void wpack(
    const float* __restrict__ Wm, unsigned short* __restrict__ bphi, unsigned short* __restrict__ bplo)
{
    int s = blockIdx.x * 256 + threadIdx.x;   // grid 8 x 256 = 2048
    if (s >= 2048) return;
    int n    = s >> 8;
    int kt   = (s >> 6) & 3;
    int lane = s & 63;
    int col  = n * 16 + (lane & 15);
    int krow = kt * 32 + ((lane >> 4) << 3);
    #pragma unroll
    for (int j = 0; j < 8; ++j) {
        float x = Wm[(size_t)(krow + j) * EMB + col];
        unsigned short hi = f2bf(x);
        unsigned short lo = f2bf(x - bf2f(hi));
        bphi[(size_t)s * 8 + j] = hi;
        bplo[(size_t)s * 8 + j] = lo;
    }
}

// ---------------- MFMA GEMM: feat = h @ W (bf16x3), fused el/er ----------------
__global__ __launch_bounds__(256) void mfma_gemm(
    const unsigned short* __restrict__ hhi, const unsigned short* __restrict__ hlo,
    const unsigned short* __restrict__ bphi, const unsigned short* __restrict__ bplo,
    const float* __restrict__ alv, const float* __restrict__ arv,
    unsigned short* __restrict__ feat_bf, float* __restrict__ el, float* __restrict__ er)
{
    const int lane = threadIdx.x & 63;
    const int wave = threadIdx.x >> 6;
    const int rowbase = blockIdx.x * 64 + wave * 16;

    f32x4 acc[8];
    #pragma unroll
    for (int nn = 0; nn < 8; ++nn) acc[nn] = (f32x4){0.f, 0.f, 0.f, 0.f};

    const int ar  = rowbase + (lane & 15);
    const int car = ar < NND ? ar : NND - 1;
    const int kofs = (lane >> 4) * 8;

    #pragma unroll
    for (int kt = 0; kt < 4; ++kt) {
        const int k0 = kt * 32 + kofs;
        short8v ah = *reinterpret_cast<const short8v*>(hhi + (size_t)car * EMB + k0);
        short8v av = *reinterpret_cast<const short8v*>(hlo + (size_t)car * EMB + k0);
        #pragma unroll
        for (int nn = 0; nn < 8; ++nn) {
            const size_t bofs = ((size_t)(nn * 4 + kt) * 64 + lane) * 8;
            short8v bh = *reinterpret_cast<const short8v*>(bphi + bofs);
            short8v bl = *reinterpret_cast<const short8v*>(bplo + bofs);
            acc[nn] = __builtin_amdgcn_mfma_f32_16x16x32_bf16(ah, bh, acc[nn], 0, 0, 0);
            acc[nn] = __builtin_amdgcn_mfma_f32_16x16x32_bf16(av, bh, acc[nn], 0, 0, 0);
            acc[nn] = __builtin_amdgcn_mfma_f32_16x16x32_bf16(ah, bl, acc[nn], 0, 0, 0);
        }
    }

    const int colr = lane & 15;
    const int rgrp = lane >> 4;
    const int row0 = rowbase + rgrp * 4;
    #pragma unroll
    for (int nn = 0; nn < 8; ++nn) {
        f32x4 a = acc[nn];
        #pragma unroll
        for (int r = 0; r < 4; ++r) {
            if (row0 + r < NND)
                feat_bf[(size_t)(row0 + r) * EMB + nn * 16 + colr] = f2bf(a[r]);
        }
        const float alc = alv[nn * 16 + colr];
        const float arc = arv[nn * 16 + colr];
        float pl[4], pr[4];
        #pragma unroll
        for (int r = 0; r < 4; ++r) { pl[r] = a[r] * alc; pr[r] = a[r] * arc; }
        #pragma unroll
        for (int mask = 1; mask < 16; mask <<= 1) {
            #pragma unroll
            for (int r = 0; r < 4; ++r) {
                pl[r] += __shfl_xor(pl[r], mask);
                pr[r] += __shfl_xor(pr[r], mask);
            }
        }
        if (colr == 0) {
            #pragma unroll
            for (int r = 0; r < 4; ++r) {
                int row = row0 + r;
                if (row < NND) {
                    el[row * NH + nn] = pl[r];
                    er[row * NH + nn] = pr[r];
                }
            }
        }
    }
}

// ---------------- CSR build (per path; reused across both layers) ----------------
__global__ __launch_bounds__(256) void deg_count(const int* __restrict__ dst, int* __restrict__ deg)
{
    int e = blockIdx.x * blockDim.x + threadIdx.x;
    if (e < NE) atomicAdd(&deg[dst[e]], 1);
}

// single-block exclusive scan; also seeds per-bucket append cursors bcur[b]=rowptr[b*512]
__global__ __launch_bounds__(1024) void scan_deg(const int* __restrict__ deg,
                                                 int* __restrict__ rowptr, int* __restrict__ bcur)
{
    __shared__ int ssum[1024];
    const int t  = threadIdx.x;
    const int CH = (NND + 1023) / 1024;
    const int base = t * CH;
    int s = 0;
    for (int j = 0; j < CH; ++j) {
        int idx = base + j;
        if (idx < NND) s += deg[idx];
    }
    ssum[t] = s;
    __syncthreads();
    for (int off = 1; off < 1024; off <<= 1) {
        int v = (t >= off) ? ssum[t - off] : 0;
        __syncthreads();
        ssum[t] += v;
        __syncthreads();
    }
    int run = (t > 0) ? ssum[t - 1] : 0;
    for (int j = 0; j < CH; ++j) {
        int idx = base + j;
        if (idx < NND) {
            rowptr[idx] = run;
            run += deg[idx];
        }
    }
    if (t == 1023) rowptr[NND] = run;
    __syncthreads();
    if (t < NB) bcur[t] = rowptr[t << 9];
}

// B1: bucket edges by dst>>9 into ebuf (contiguous per-block runs per bucket).
// Block: 256 threads x 8 edges = 2048 edges.
__global__ __launch_bounds__(256) void bucket_scatter(
    const int* __restrict__ src, const int* __restrict__ dst,
    int* __restrict__ bcur, int2* __restrict__ ebuf)
{
    __shared__ int hist[NB];
    __shared__ int base[NB];
    __shared__ int lcur[NB];
    const int t  = threadIdx.x;
    const int e0 = blockIdx.x * 2048 + t * 8;

    for (int b = t; b < NB; b += 256) { hist[b] = 0; lcur[b] = 0; }
    __syncthreads();

    int sj[8], dj[8];
    bool vj[8];
    #pragma unroll
    for (int j = 0; j < 8; ++j) {
        int e = e0 + j;
        vj[j] = (e < NE);
        if (vj[j]) {
            sj[j] = src[e];
            dj[j] = dst[e];
            atomicAdd(&hist[dj[j] >> 9], 1);
        }
    }
    __syncthreads();
    for (int b = t; b < NB; b += 256) {
        int c = hist[b];
        base[b] = c > 0 ? atomicAdd(&bcur[b], c) : 0;
    }
    __syncthreads();
    #pragma unroll
    for (int j = 0; j < 8; ++j) {
        if (vj[j]) {
            int b   = dj[j] >> 9;
            int off = atomicAdd(&lcur[b], 1);
            ebuf[(size_t)base[b] + off] = make_int2(sj[j], dj[j]);
        }
    }
}

// B2: one block per bucket; LDS cursors over the 512-node window; CSR writes
// confined to the bucket's ~64 KB csr window (L2-resident).
__global__ __launch_bounds__(1024) void bucket_fill(
    const int* __restrict__ rowptr, const int2* __restrict__ ebuf,
    int* __restrict__ csrsrc)
{
    __shared__ int cur[512];
    const int b    = blockIdx.x;
    const int n0   = b << 9;
    const int nend = (n0 + 512 < NND) ? n0 + 512 : NND;
    const int t    = threadIdx.x;
    if (t < 512 && n0 + t < NND) cur[t] = rowptr[n0 + t];
    __syncthreads();
    const int eA = rowptr[n0];
    const int eB = rowptr[nend];
    for (int i = eA + t; i < eB; i += 1024) {
        int2 ed = ebuf[i];
        int p = atomicAdd(&cur[ed.y - n0], 1);
        csrsrc[p] = ed.x;
    }
}

// ---------------- Gather-aggregate: one wave per destination node ----------------
__global__ __launch_bounds__(256) void gather_agg(
    const int* __restrict__ rowptr, const int* __restrict__ csrsrc,
    const float* __restrict__ el, const float* __restrict__ er,
    const unsigned int* __restrict__ featu,
    const float* __restrict__ hin_f32,          // layer1 residual (fs) or null
    const unsigned int* __restrict__ hin_hi,    // layer2 residual (hi/lo) or null
    const unsigned int* __restrict__ hin_lo,
    const float* __restrict__ bias,
    float* __restrict__ esum_out,
    float* __restrict__ hout_f32,               // layer2 out or null
    unsigned int* __restrict__ hhi_out,         // layer1 out or null
    unsigned int* __restrict__ hlo_out)
{
    const int wid  = (blockIdx.x * blockDim.x + threadIdx.x) >> 6;
    const int lane = threadIdx.x & 63;
    if (wid >= NND) return;
    const int n  = wid;
    const int h  = lane >> 3;   // head (softmax + feat dims)
    const int j8 = lane & 7;    // edge slot in chunk

    const float ern = er[n * NH + h];
    const int r0 = __builtin_amdgcn_readfirstlane(rowptr[n]);
    const int r1 = __builtin_amdgcn_readfirstlane(rowptr[n + 1]);

    float acc0 = 0.f, acc1 = 0.f, es = 0.f;

    for (int i = r0; i < r1; i += 8) {
        const int m = r1 - i;                              // wave-uniform
        int idx = i + j8;
        int sv  = csrsrc[idx < r1 ? idx : (r1 - 1)];
        float w = 0.f;
        if (j8 < m) w = expf(lrelu(el[sv * NH + h] + ern));
        #pragma unroll
        for (int j = 0; j < 8; ++j) {
            if (j >= m) break;                             // uniform
            int   sj = __shfl(sv, j);
            float wj = __shfl(w, (lane & 56) | j);
            unsigned int v = featu[(size_t)sj * 64 + lane];
            float f0 = __uint_as_float(v << 16);
            float f1 = __uint_as_float(v & 0xffff0000u);
            es  += wj;
            acc0 = fmaf(wj, f0, acc0);
            acc1 = fmaf(wj, f1, acc1);
        }
    }

    if (j8 == 0) esum_out[n * NH + h] = es;
    const float inv = 1.f / fmaxf(es, 1e-9f);

    float h0, h1;
    if (hin_f32) {
        float2 hv = reinterpret_cast<const float2*>(hin_f32)[(size_t)n * 64 + lane];
        h0 = hv.x; h1 = hv.y;
    } else {
        unsigned int hiu = hin_hi[(size_t)n * 64 + lane];
        unsigned int lou = hin_lo[(size_t)n * 64 + lane];
        h0 = __uint_as_float(hiu << 16) + __uint_as_float(lou << 16);
        h1 = __uint_as_float(hiu & 0xffff0000u) + __uint_as_float(lou & 0xffff0000u);
    }
    float o0 = elu(fmaf(acc0, inv, h0 + bias[lane * 2]));
    float o1 = elu(fmaf(acc1, inv, h1 + bias[lane * 2 + 1]));

    if (hout_f32) {
        reinterpret_cast<float2*>(hout_f32)[(size_t)n * 64 + lane] = make_float2(o0, o1);
    } else {
        unsigned short hi0 = f2bf(o0), hi1 = f2bf(o1);
        unsigned short lo0 = f2bf(o0 - bf2f(hi0)), lo1 = f2bf(o1 - bf2f(hi1));
        hhi_out[(size_t)n * 64 + lane] = (unsigned int)hi0 | ((unsigned int)hi1 << 16);
        hlo_out[(size_t)n * 64 + lane] = (unsigned int)lo0 | ((unsigned int)lo1 << 16);
    }
}

// ---------------- alpha in original edge order (last layer only) ----------------
__global__ __launch_bounds__(256) void alpha_write(
    const int* __restrict__ src, const int* __restrict__ dst,
    const float* __restrict__ el, const float* __restrict__ er,
    const float* __restrict__ esum, float* __restrict__ aout)
{
    int tid = blockIdx.x * blockDim.x + threadIdx.x;
    if (tid >= NE * NH) return;
    int e = tid >> 3;
    int h = tid & 7;
    int s = src[e], d = dst[e];
    float x = lrelu(el[s * NH + h] + er[d * NH + h]);
    float a = expf(x) / fmaxf(esum[d * NH + h], 1e-9f);
    aout[(size_t)e * NH + h] = a;
}

extern "C" void kernel_launch(void* const* d_in, const int* in_sizes, int n_in,
                              void* d_out, int out_size, void* d_ws, size_t ws_size,
                              hipStream_t stream) {
    const float* fs   = (const float*)d_in[0];  // [2][N][128]
    const float* W    = (const float*)d_in[1];  // [2][2][128][128]
    const float* al   = (const float*)d_in[2];  // [2][2][8][16]
    const float* ar   = (const float*)d_in[3];  // [2][2][8][16]
    const float* bias = (const float*)d_in[4];  // [2][2][128]
    const int*   edges= (const int*)d_in[5];    // [2][2][E]

    float* out       = (float*)d_out;
    float* out_emb   = out;                              // [2][N][128]
    float* out_alpha = out + (size_t)2 * NND * EMB;      // [2][E][8]

    char* ws = (char*)d_ws;
    unsigned short* feat_bf = (unsigned short*)ws; ws += (size_t)NND * EMB * 2;
    unsigned short* hhi     = (unsigned short*)ws; ws += (size_t)NND * EMB * 2;
    unsigned short* hlo     = (unsigned short*)ws; ws += (size_t)NND * EMB * 2;
    float*          el      = (float*)ws;          ws += (size_t)NND * NH * 4;
    float*          er      = (float*)ws;          ws += (size_t)NND * NH * 4;
    float*          esum    = (float*)ws;          ws += (size_t)NND * NH * 4;
    int*            deg     = (int*)ws;            ws += (size_t)NND * 4;
    int*            rowptr  = (int*)ws;            ws += (size_t)(NND + 1) * 4;
    int*            bcur    = (int*)ws;            ws += (size_t)128 * 4;
    int*            csrsrc  = (int*)ws;            ws += (size_t)NE * 4;
    int2*           ebuf    = (int2*)ws;           ws += (size_t)NE * 8;
    unsigned short* bphi    = (unsigned short*)ws; ws += (size_t)16384 * 2;
    unsigned short* bplo    = (unsigned short*)ws; ws += (size_t)16384 * 2;

    unsigned int* featu = (unsigned int*)feat_bf;
    unsigned int* hhi_u = (unsigned int*)hhi;
    unsigned int* hlo_u = (unsigned int*)hlo;

    for (int p = 0; p < 2; ++p) {
        const int* src = edges + (size_t)p * 2 * NE;
        const int* dst = src + NE;

        hipMemsetAsync(deg, 0, (size_t)NND * 4, stream);
        deg_count<<<(NE + 255) / 256, 256, 0, stream>>>(dst, deg);
        scan_deg<<<1, 1024, 0, stream>>>(deg, rowptr, bcur);
        bucket_scatter<<<(NE + 2047) / 2048, 256, 0, stream>>>(src, dst, bcur, ebuf);
        bucket_fill<<<NB, 1024, 0, stream>>>(rowptr, ebuf, csrsrc);

        for (int l = 0; l < 2; ++l) {
            const float* fsp  = fs + (size_t)p * NND * EMB;
            const float* Wl   = W    + (size_t)(p * 2 + l) * EMB * EMB;
            const float* alv  = al   + (size_t)(p * 2 + l) * NH * HD;
            const float* arv  = ar   + (size_t)(p * 2 + l) * NH * HD;
            const float* bl   = bias + (size_t)(p * 2 + l) * EMB;

            wpack<<<8, 256, 0, stream>>>(Wl, bphi, bplo);
            if (l == 0)
                hsplit<<<NND * EMB / 8 / 256, 256, 0, stream>>>(fsp, hhi, hlo);

            mfma_gemm<<<(NND + 63) / 64, 256, 0, stream>>>(hhi, hlo, bphi, bplo, alv, arv, feat_bf, el, er);

            if (l == 0) {
                gather_agg<<<(NND + 3) / 4, 256, 0, stream>>>(
                    rowptr, csrsrc, el, er, featu,
                    fsp, nullptr, nullptr, bl, esum,
                    nullptr, hhi_u, hlo_u);
            } else {
                gather_agg<<<(NND + 3) / 4, 256, 0, stream>>>(
                    rowptr, csrsrc, el, er, featu,
                    nullptr, hhi_u, hlo_u, bl, esum,
                    out_emb + (size_t)p * NND * EMB, nullptr, nullptr);
                alpha_write<<<((size_t)NE * NH + 255) / 256, 256, 0, stream>>>(
                    src, dst, el, er, esum, out_alpha + (size_t)p * NE * NH);
            }
        }
    }
}

// Round 7
// 941.866 us; speedup vs baseline: 52.4143x; 1.2163x over previous
//
#include <hip/hip_runtime.h>
#include <hip/hip_bf16.h>

#define NND 50000
#define NE  1600000
#define EMB 128
#define NH  8
#define HD  16
#define NB  98            // ceil(50000/512) buckets of 512 dst nodes

typedef __attribute__((ext_vector_type(8))) short short8v;
typedef __attribute__((ext_vector_type(4))) float f32x4;

__device__ __forceinline__ float lrelu(float x) { return x > 0.f ? x : 0.2f * x; }
__device__ __forceinline__ float elu(float x)   { return x > 0.f ? x : expm1f(x); }

__device__ __forceinline__ unsigned short f2bf(float x) {
    __hip_bfloat16 b = __float2bfloat16(x);
    return *reinterpret_cast<unsigned short*>(&b);
}
__device__ __forceinline__ float bf2f(unsigned short u) {
    __hip_bfloat16 b = *reinterpret_cast<__hip_bfloat16*>(&u);
    return __bfloat162float(b);
}

// ---------------- split h into bf16 hi/lo (x ~= hi + lo) ----------------
__global__ __launch_bounds__(256) void hsplit(
    const float* __restrict__ hin, unsigned short* __restrict__ hhi, unsigned short* __restrict__ hlo)
{
    int idx = blockIdx.x * 256 + threadIdx.x;   // each handles 8 floats; grid exact
    const float4* h4 = reinterpret_cast<const float4*>(hin);
    float4 v0 = h4[(size_t)idx * 2];
    float4 v1 = h4[(size_t)idx * 2 + 1];
    float xs[8] = { v0.x, v0.y, v0.z, v0.w, v1.x, v1.y, v1.z, v1.w };
    unsigned short hi[8], lo[8];
    #pragma unroll
    for (int j = 0; j < 8; ++j) {
        hi[j] = f2bf(xs[j]);
        lo[j] = f2bf(xs[j] - bf2f(hi[j]));
    }
    *reinterpret_cast<uint4*>(hhi + (size_t)idx * 8) = *reinterpret_cast<uint4*>(hi);
    *reinterpret_cast<uint4*>(hlo + (size_t)idx * 8) = *reinterpret_cast<uint4*>(lo);
}

// ---------------- pack W into per-fragment bf16 hi/lo layout ----------------
// bp[(n*4+kt)*64+lane][j] = W[kt*32 + (lane>>4)*8 + j][n*16 + (lane&15)]
__global__ __launch_bounds__(256) void wpack(
    const float* __restrict__ Wm, unsigned short* __restrict__ bphi, unsigned short* __restrict__ bplo)
{
    int s = blockIdx.x * 256 + threadIdx.x;   // grid 8 x 256 = 2048
    if (s >= 2048) return;
    int n    = s >> 8;
    int kt   = (s >> 6) & 3;
    int lane = s & 63;
    int col  = n * 16 + (lane & 15);
    int krow = kt * 32 + ((lane >> 4) << 3);
    #pragma unroll
    for (int j = 0; j < 8; ++j) {
        float x = Wm[(size_t)(krow + j) * EMB + col];
        unsigned short hi = f2bf(x);
        unsigned short lo = f2bf(x - bf2f(hi));
        bphi[(size_t)s * 8 + j] = hi;
        bplo[(size_t)s * 8 + j] = lo;
    }
}

// ---------------- MFMA GEMM: feat = h @ W (bf16x3), fused el/er ----------------
// Block 256 = 4 waves; wave w handles 16 rows x 32 cols (heads 2w, 2w+1).
// Grid = N/16 blocks -> ~12500 waves for latency hiding.
__global__ __launch_bounds__(256) void mfma_gemm(
    const unsigned short* __restrict__ hhi, const unsigned short* __restrict__ hlo,
    const unsigned short* __restrict__ bphi, const unsigned short* __restrict__ bplo,
    const float* __restrict__ alv, const float* __restrict__ arv,
    unsigned short* __restrict__ feat_bf, float* __restrict__ el, float* __restrict__ er)
{
    const int lane = threadIdx.x & 63;
    const int wave = threadIdx.x >> 6;
    const int rowbase = blockIdx.x * 16;

    f32x4 acc[2];
    acc[0] = (f32x4){0.f, 0.f, 0.f, 0.f};
    acc[1] = (f32x4){0.f, 0.f, 0.f, 0.f};

    const int ar  = rowbase + (lane & 15);
    const int car = ar < NND ? ar : NND - 1;
    const int kofs = (lane >> 4) * 8;

    #pragma unroll
    for (int kt = 0; kt < 4; ++kt) {
        const int k0 = kt * 32 + kofs;
        short8v ah = *reinterpret_cast<const short8v*>(hhi + (size_t)car * EMB + k0);
        short8v av = *reinterpret_cast<const short8v*>(hlo + (size_t)car * EMB + k0);
        #pragma unroll
        for (int q = 0; q < 2; ++q) {
            const int nn = wave * 2 + q;
            const size_t bofs = ((size_t)(nn * 4 + kt) * 64 + lane) * 8;
            short8v bh = *reinterpret_cast<const short8v*>(bphi + bofs);
            short8v bl = *reinterpret_cast<const short8v*>(bplo + bofs);
            acc[q] = __builtin_amdgcn_mfma_f32_16x16x32_bf16(ah, bh, acc[q], 0, 0, 0);
            acc[q] = __builtin_amdgcn_mfma_f32_16x16x32_bf16(av, bh, acc[q], 0, 0, 0);
            acc[q] = __builtin_amdgcn_mfma_f32_16x16x32_bf16(ah, bl, acc[q], 0, 0, 0);
        }
    }

    const int colr = lane & 15;
    const int rgrp = lane >> 4;
    const int row0 = rowbase + rgrp * 4;
    #pragma unroll
    for (int q = 0; q < 2; ++q) {
        const int nn = wave * 2 + q;
        f32x4 a = acc[q];
        #pragma unroll
        for (int r = 0; r < 4; ++r) {
            if (row0 + r < NND)
                feat_bf[(size_t)(row0 + r) * EMB + nn * 16 + colr] = f2bf(a[r]);
        }
        const float alc = alv[nn * 16 + colr];
        const float arc = arv[nn * 16 + colr];
        float pl[4], pr[4];
        #pragma unroll
        for (int r = 0; r < 4; ++r) { pl[r] = a[r] * alc; pr[r] = a[r] * arc; }
        #pragma unroll
        for (int mask = 1; mask < 16; mask <<= 1) {
            #pragma unroll
            for (int r = 0; r < 4; ++r) {
                pl[r] += __shfl_xor(pl[r], mask);
                pr[r] += __shfl_xor(pr[r], mask);
            }
        }
        if (colr == 0) {
            #pragma unroll
            for (int r = 0; r < 4; ++r) {
                int row = row0 + r;
                if (row < NND) {
                    el[row * NH + nn] = pl[r];
                    er[row * NH + nn] = pr[r];
                }
            }
        }
    }
}

// ---------------- CSR build (per path; reused across both layers) ----------------
__global__ __launch_bounds__(256) void deg_count(const int* __restrict__ dst, int* __restrict__ deg)
{
    int e = blockIdx.x * blockDim.x + threadIdx.x;
    if (e < NE) atomicAdd(&deg[dst[e]], 1);
}

// single-block exclusive scan; also seeds per-bucket append cursors bcur[b]=rowptr[b*512]
__global__ __launch_bounds__(1024) void scan_deg(const int* __restrict__ deg,
                                                 int* __restrict__ rowptr, int* __restrict__ bcur)
{
    __shared__ int ssum[1024];
    const int t  = threadIdx.x;
    const int CH = (NND + 1023) / 1024;
    const int base = t * CH;
    int s = 0;
    for (int j = 0; j < CH; ++j) {
        int idx = base + j;
        if (idx < NND) s += deg[idx];
    }
    ssum[t] = s;
    __syncthreads();
    for (int off = 1; off < 1024; off <<= 1) {
        int v = (t >= off) ? ssum[t - off] : 0;
        __syncthreads();
        ssum[t] += v;
        __syncthreads();
    }
    int run = (t > 0) ? ssum[t - 1] : 0;
    for (int j = 0; j < CH; ++j) {
        int idx = base + j;
        if (idx < NND) {
            rowptr[idx] = run;
            run += deg[idx];
        }
    }
    if (t == 1023) rowptr[NND] = run;
    __syncthreads();
    if (t < NB) bcur[t] = rowptr[t << 9];
}

// B1: bucket edges by dst>>9 into ebuf (contiguous per-block runs per bucket).
__global__ __launch_bounds__(256) void bucket_scatter(
    const int* __restrict__ src, const int* __restrict__ dst,
    int* __restrict__ bcur, int2* __restrict__ ebuf)
{
    __shared__ int hist[NB];
    __shared__ int base[NB];
    __shared__ int lcur[NB];
    const int t  = threadIdx.x;
    const int e0 = blockIdx.x * 2048 + t * 8;

    for (int b = t; b < NB; b += 256) { hist[b] = 0; lcur[b] = 0; }
    __syncthreads();

    int sj[8], dj[8];
    bool vj[8];
    #pragma unroll
    for (int j = 0; j < 8; ++j) {
        int e = e0 + j;
        vj[j] = (e < NE);
        if (vj[j]) {
            sj[j] = src[e];
            dj[j] = dst[e];
            atomicAdd(&hist[dj[j] >> 9], 1);
        }
    }
    __syncthreads();
    for (int b = t; b < NB; b += 256) {
        int c = hist[b];
        base[b] = c > 0 ? atomicAdd(&bcur[b], c) : 0;
    }
    __syncthreads();
    #pragma unroll
    for (int j = 0; j < 8; ++j) {
        if (vj[j]) {
            int b   = dj[j] >> 9;
            int off = atomicAdd(&lcur[b], 1);
            ebuf[(size_t)base[b] + off] = make_int2(sj[j], dj[j]);
        }
    }
}

// B2: one block per bucket; LDS cursors; CSR writes stay in an L2-resident window.
__global__ __launch_bounds__(1024) void bucket_fill(
    const int* __restrict__ rowptr, const int2* __restrict__ ebuf,
    int* __restrict__ csrsrc)
{
    __shared__ int cur[512];
    const int b    = blockIdx.x;
    const int n0   = b << 9;
    const int nend = (n0 + 512 < NND) ? n0 + 512 : NND;
    const int t    = threadIdx.x;
    if (t < 512 && n0 + t < NND) cur[t] = rowptr[n0 + t];
    __syncthreads();
    const int eA = rowptr[n0];
    const int eB = rowptr[nend];
    for (int i = eA + t; i < eB; i += 1024) {
        int2 ed = ebuf[i];
        int p = atomicAdd(&cur[ed.y - n0], 1);
        csrsrc[p] = ed.x;
    }
}

// ---------------- Gather-aggregate: one wave per destination node ----------------
// Full chunks: all 8 feat loads issued back-to-back (8x MLP), no branches.
__global__ __launch_bounds__(256) void gather_agg(
    const int* __restrict__ rowptr, const int* __restrict__ csrsrc,
    const float* __restrict__ el, const float* __restrict__ er,
    const unsigned int* __restrict__ featu,
    const float* __restrict__ hin_f32,          // layer1 residual (fs) or null
    const unsigned int* __restrict__ hin_hi,    // layer2 residual (hi/lo) or null
    const unsigned int* __restrict__ hin_lo,
    const float* __restrict__ bias,
    float* __restrict__ esum_out,
    float* __restrict__ hout_f32,               // layer2 out or null
    unsigned int* __restrict__ hhi_out,         // layer1 out or null
    unsigned int* __restrict__ hlo_out)
{
    const int wid  = (blockIdx.x * blockDim.x + threadIdx.x) >> 6;
    const int lane = threadIdx.x & 63;
    if (wid >= NND) return;
    const int n  = wid;
    const int h  = lane >> 3;   // head (softmax + feat dims)
    const int j8 = lane & 7;    // edge slot in chunk

    const float ern = er[n * NH + h];
    const int r0 = __builtin_amdgcn_readfirstlane(rowptr[n]);
    const int r1 = __builtin_amdgcn_readfirstlane(rowptr[n + 1]);

    float acc0 = 0.f, acc1 = 0.f, es = 0.f;

    const int nfull = r0 + ((r1 - r0) & ~7);
    int i = r0;
    for (; i < nfull; i += 8) {
        int   sv = csrsrc[i + j8];
        float w  = expf(lrelu(el[sv * NH + h] + ern));
        int sjs[8];
        #pragma unroll
        for (int j = 0; j < 8; ++j) sjs[j] = __shfl(sv, j);
        unsigned int vs[8];
        #pragma unroll
        for (int j = 0; j < 8; ++j) vs[j] = featu[(size_t)sjs[j] * 64 + lane];
        #pragma unroll
        for (int j = 0; j < 8; ++j) {
            float wj = __shfl(w, (lane & 56) | j);
            es  += wj;
            acc0 = fmaf(wj, __uint_as_float(vs[j] << 16), acc0);
            acc1 = fmaf(wj, __uint_as_float(vs[j] & 0xffff0000u), acc1);
        }
    }
    if (i < r1) {
        const int m = r1 - i;                              // 1..7, wave-uniform
        int idx = i + j8;
        int sv  = csrsrc[idx < r1 ? idx : (r1 - 1)];
        float w = 0.f;
        if (j8 < m) w = expf(lrelu(el[sv * NH + h] + ern));
        #pragma unroll
        for (int j = 0; j < 8; ++j) {
            if (j >= m) break;                             // uniform
            int   sj = __shfl(sv, j);
            float wj = __shfl(w, (lane & 56) | j);
            unsigned int v = featu[(size_t)sj * 64 + lane];
            es  += wj;
            acc0 = fmaf(wj, __uint_as_float(v << 16), acc0);
            acc1 = fmaf(wj, __uint_as_float(v & 0xffff0000u), acc1);
        }
    }

    if (j8 == 0) esum_out[n * NH + h] = es;
    const float inv = 1.f / fmaxf(es, 1e-9f);

    float h0, h1;
    if (hin_f32) {
        float2 hv = reinterpret_cast<const float2*>(hin_f32)[(size_t)n * 64 + lane];
        h0 = hv.x; h1 = hv.y;
    } else {
        unsigned int hiu = hin_hi[(size_t)n * 64 + lane];
        unsigned int lou = hin_lo[(size_t)n * 64 + lane];
        h0 = __uint_as_float(hiu << 16) + __uint_as_float(lou << 16);
        h1 = __uint_as_float(hiu & 0xffff0000u) + __uint_as_float(lou & 0xffff0000u);
    }
    float o0 = elu(fmaf(acc0, inv, h0 + bias[lane * 2]));
    float o1 = elu(fmaf(acc1, inv, h1 + bias[lane * 2 + 1]));

    if (hout_f32) {
        reinterpret_cast<float2*>(hout_f32)[(size_t)n * 64 + lane] = make_float2(o0, o1);
    } else {
        unsigned short hi0 = f2bf(o0), hi1 = f2bf(o1);
        unsigned short lo0 = f2bf(o0 - bf2f(hi0)), lo1 = f2bf(o1 - bf2f(hi1));
        hhi_out[(size_t)n * 64 + lane] = (unsigned int)hi0 | ((unsigned int)hi1 << 16);
        hlo_out[(size_t)n * 64 + lane] = (unsigned int)lo0 | ((unsigned int)lo1 << 16);
    }
}

// ---------------- alpha in original edge order (last layer only) ----------------
__global__ __launch_bounds__(256) void alpha_write(
    const int* __restrict__ src, const int* __restrict__ dst,
    const float* __restrict__ el, const float* __restrict__ er,
    const float* __restrict__ esum, float* __restrict__ aout)
{
    int tid = blockIdx.x * blockDim.x + threadIdx.x;
    if (tid >= NE * NH) return;
    int e = tid >> 3;
    int h = tid & 7;
    int s = src[e], d = dst[e];
    float x = lrelu(el[s * NH + h] + er[d * NH + h]);
    float a = expf(x) / fmaxf(esum[d * NH + h], 1e-9f);
    aout[(size_t)e * NH + h] = a;
}

extern "C" void kernel_launch(void* const* d_in, const int* in_sizes, int n_in,
                              void* d_out, int out_size, void* d_ws, size_t ws_size,
                              hipStream_t stream) {
    const float* fs   = (const float*)d_in[0];  // [2][N][128]
    const float* W    = (const float*)d_in[1];  // [2][2][128][128]
    const float* al   = (const float*)d_in[2];  // [2][2][8][16]
    const float* ar   = (const float*)d_in[3];  // [2][2][8][16]
    const float* bias = (const float*)d_in[4];  // [2][2][128]
    const int*   edges= (const int*)d_in[5];    // [2][2][E]

    float* out       = (float*)d_out;
    float* out_emb   = out;                              // [2][N][128]
    float* out_alpha = out + (size_t)2 * NND * EMB;      // [2][E][8]

    char* ws = (char*)d_ws;
    unsigned short* feat_bf = (unsigned short*)ws; ws += (size_t)NND * EMB * 2;
    unsigned short* hhi     = (unsigned short*)ws; ws += (size_t)NND * EMB * 2;
    unsigned short* hlo     = (unsigned short*)ws; ws += (size_t)NND * EMB * 2;
    float*          el      = (float*)ws;          ws += (size_t)NND * NH * 4;
    float*          er      = (float*)ws;          ws += (size_t)NND * NH * 4;
    float*          esum    = (float*)ws;          ws += (size_t)NND * NH * 4;
    int*            deg     = (int*)ws;            ws += (size_t)NND * 4;
    int*            rowptr  = (int*)ws;            ws += (size_t)(NND + 1) * 4;
    int*            bcur    = (int*)ws;            ws += (size_t)128 * 4;
    int*            csrsrc  = (int*)ws;            ws += (size_t)NE * 4;
    int2*           ebuf    = (int2*)ws;           ws += (size_t)NE * 8;
    unsigned short* bphi    = (unsigned short*)ws; ws += (size_t)16384 * 2;
    unsigned short* bplo    = (unsigned short*)ws; ws += (size_t)16384 * 2;

    unsigned int* featu = (unsigned int*)feat_bf;
    unsigned int* hhi_u = (unsigned int*)hhi;
    unsigned int* hlo_u = (unsigned int*)hlo;

    for (int p = 0; p < 2; ++p) {
        const int* src = edges + (size_t)p * 2 * NE;
        const int* dst = src + NE;

        hipMemsetAsync(deg, 0, (size_t)NND * 4, stream);
        deg_count<<<(NE + 255) / 256, 256, 0, stream>>>(dst, deg);
        scan_deg<<<1, 1024, 0, stream>>>(deg, rowptr, bcur);
        bucket_scatter<<<(NE + 2047) / 2048, 256, 0, stream>>>(src, dst, bcur, ebuf);
        bucket_fill<<<NB, 1024, 0, stream>>>(rowptr, ebuf, csrsrc);

        for (int l = 0; l < 2; ++l) {
            const float* fsp  = fs + (size_t)p * NND * EMB;
            const float* Wl   = W    + (size_t)(p * 2 + l) * EMB * EMB;
            const float* alv  = al   + (size_t)(p * 2 + l) * NH * HD;
            const float* arv  = ar   + (size_t)(p * 2 + l) * NH * HD;
            const float* bl   = bias + (size_t)(p * 2 + l) * EMB;

            wpack<<<8, 256, 0, stream>>>(Wl, bphi, bplo);
            if (l == 0)
                hsplit<<<NND * EMB / 8 / 256, 256, 0, stream>>>(fsp, hhi, hlo);

            mfma_gemm<<<(NND + 15) / 16, 256, 0, stream>>>(hhi, hlo, bphi, bplo, alv, arv, feat_bf, el, er);

            if (l == 0) {
                gather_agg<<<(NND + 3) / 4, 256, 0, stream>>>(
                    rowptr, csrsrc, el, er, featu,
                    fsp, nullptr, nullptr, bl, esum,
                    nullptr, hhi_u, hlo_u);
            } else {
                gather_agg<<<(NND + 3) / 4, 256, 0, stream>>>(
                    rowptr, csrsrc, el, er, featu,
                    nullptr, hhi_u, hlo_u, bl, esum,
                    out_emb + (size_t)p * NND * EMB, nullptr, nullptr);
                alpha_write<<<((size_t)NE * NH + 255) / 256, 256, 0, stream>>>(
                    src, dst, el, er, esum, out_alpha + (size_t)p * NE * NH);
            }
        }
    }
}

// Round 8
// 690.410 us; speedup vs baseline: 71.5043x; 1.3642x over previous
//
#include <hip/hip_runtime.h>
#include <hip/hip_bf16.h>

#define NND 50000
#define NE  1600000
#define EMB 128
#define NH  8
#define HD  16
#define NB  98            // ceil(50000/512) buckets of 512 dst nodes

typedef __attribute__((ext_vector_type(8))) short short8v;
typedef __attribute__((ext_vector_type(4))) float f32x4;

__device__ __forceinline__ float lrelu(float x) { return x > 0.f ? x : 0.2f * x; }
__device__ __forceinline__ float elu(float x)   { return x > 0.f ? x : expm1f(x); }

__device__ __forceinline__ unsigned short f2bf(float x) {
    __hip_bfloat16 b = __float2bfloat16(x);
    return *reinterpret_cast<unsigned short*>(&b);
}
__device__ __forceinline__ float bf2f(unsigned short u) {
    __hip_bfloat16 b = *reinterpret_cast<__hip_bfloat16*>(&u);
    return __bfloat162float(b);
}

// ---------------- split h into bf16 hi/lo (x ~= hi + lo) ----------------
__global__ __launch_bounds__(256) void hsplit(
    const float* __restrict__ hin, unsigned short* __restrict__ hhi, unsigned short* __restrict__ hlo)
{
    int idx = blockIdx.x * 256 + threadIdx.x;   // each handles 8 floats; grid exact
    const float4* h4 = reinterpret_cast<const float4*>(hin);
    float4 v0 = h4[(size_t)idx * 2];
    float4 v1 = h4[(size_t)idx * 2 + 1];
    float xs[8] = { v0.x, v0.y, v0.z, v0.w, v1.x, v1.y, v1.z, v1.w };
    unsigned short hi[8], lo[8];
    #pragma unroll
    for (int j = 0; j < 8; ++j) {
        hi[j] = f2bf(xs[j]);
        lo[j] = f2bf(xs[j] - bf2f(hi[j]));
    }
    *reinterpret_cast<uint4*>(hhi + (size_t)idx * 8) = *reinterpret_cast<uint4*>(hi);
    *reinterpret_cast<uint4*>(hlo + (size_t)idx * 8) = *reinterpret_cast<uint4*>(lo);
}

// ---------------- pack W into per-fragment bf16 hi/lo layout ----------------
__global__ __launch_bounds__(256) void wpack(
    const float* __restrict__ Wm, unsigned short* __restrict__ bphi, unsigned short* __restrict__ bplo)
{
    int s = blockIdx.x * 256 + threadIdx.x;   // grid 8 x 256 = 2048
    if (s >= 2048) return;
    int n    = s >> 8;
    int kt   = (s >> 6) & 3;
    int lane = s & 63;
    int col  = n * 16 + (lane & 15);
    int krow = kt * 32 + ((lane >> 4) << 3);
    #pragma unroll
    for (int j = 0; j < 8; ++j) {
        float x = Wm[(size_t)(krow + j) * EMB + col];
        unsigned short hi = f2bf(x);
        unsigned short lo = f2bf(x - bf2f(hi));
        bphi[(size_t)s * 8 + j] = hi;
        bplo[(size_t)s * 8 + j] = lo;
    }
}

// ---------------- MFMA GEMM: feat = h @ W (bf16x3), fused el/er ----------------
// Block 256 = 4 waves; wave w handles 16 rows x 32 cols (heads 2w, 2w+1).
__global__ __launch_bounds__(256) void mfma_gemm(
    const unsigned short* __restrict__ hhi, const unsigned short* __restrict__ hlo,
    const unsigned short* __restrict__ bphi, const unsigned short* __restrict__ bplo,
    const float* __restrict__ alv, const float* __restrict__ arv,
    unsigned short* __restrict__ feat_bf, float* __restrict__ el, float* __restrict__ er)
{
    const int lane = threadIdx.x & 63;
    const int wave = threadIdx.x >> 6;
    const int rowbase = blockIdx.x * 16;

    f32x4 acc[2];
    acc[0] = (f32x4){0.f, 0.f, 0.f, 0.f};
    acc[1] = (f32x4){0.f, 0.f, 0.f, 0.f};

    const int ar  = rowbase + (lane & 15);
    const int car = ar < NND ? ar : NND - 1;
    const int kofs = (lane >> 4) * 8;

    #pragma unroll
    for (int kt = 0; kt < 4; ++kt) {
        const int k0 = kt * 32 + kofs;
        short8v ah = *reinterpret_cast<const short8v*>(hhi + (size_t)car * EMB + k0);
        short8v av = *reinterpret_cast<const short8v*>(hlo + (size_t)car * EMB + k0);
        #pragma unroll
        for (int q = 0; q < 2; ++q) {
            const int nn = wave * 2 + q;
            const size_t bofs = ((size_t)(nn * 4 + kt) * 64 + lane) * 8;
            short8v bh = *reinterpret_cast<const short8v*>(bphi + bofs);
            short8v bl = *reinterpret_cast<const short8v*>(bplo + bofs);
            acc[q] = __builtin_amdgcn_mfma_f32_16x16x32_bf16(ah, bh, acc[q], 0, 0, 0);
            acc[q] = __builtin_amdgcn_mfma_f32_16x16x32_bf16(av, bh, acc[q], 0, 0, 0);
            acc[q] = __builtin_amdgcn_mfma_f32_16x16x32_bf16(ah, bl, acc[q], 0, 0, 0);
        }
    }

    const int colr = lane & 15;
    const int rgrp = lane >> 4;
    const int row0 = rowbase + rgrp * 4;
    #pragma unroll
    for (int q = 0; q < 2; ++q) {
        const int nn = wave * 2 + q;
        f32x4 a = acc[q];
        #pragma unroll
        for (int r = 0; r < 4; ++r) {
            if (row0 + r < NND)
                feat_bf[(size_t)(row0 + r) * EMB + nn * 16 + colr] = f2bf(a[r]);
        }
        const float alc = alv[nn * 16 + colr];
        const float arc = arv[nn * 16 + colr];
        float pl[4], pr[4];
        #pragma unroll
        for (int r = 0; r < 4; ++r) { pl[r] = a[r] * alc; pr[r] = a[r] * arc; }
        #pragma unroll
        for (int mask = 1; mask < 16; mask <<= 1) {
            #pragma unroll
            for (int r = 0; r < 4; ++r) {
                pl[r] += __shfl_xor(pl[r], mask);
                pr[r] += __shfl_xor(pr[r], mask);
            }
        }
        if (colr == 0) {
            #pragma unroll
            for (int r = 0; r < 4; ++r) {
                int row = row0 + r;
                if (row < NND) {
                    el[row * NH + nn] = pl[r];
                    er[row * NH + nn] = pr[r];
                }
            }
        }
    }
}

// ---------------- CSR build (per path; no 50K scan anywhere) ----------------
// C1: per-bucket edge counts (LDS histogram -> 98 global atomics/block)
__global__ __launch_bounds__(256) void bucket_count(
    const int* __restrict__ dst, int* __restrict__ bcnt)
{
    __shared__ int hist[NB];
    const int t = threadIdx.x;
    for (int b = t; b < NB; b += 256) hist[b] = 0;
    __syncthreads();
    const int e0 = blockIdx.x * 2048 + t * 8;
    #pragma unroll
    for (int j = 0; j < 8; ++j) {
        int e = e0 + j;
        if (e < NE) atomicAdd(&hist[dst[e] >> 9], 1);
    }
    __syncthreads();
    for (int b = t; b < NB; b += 256)
        if (hist[b]) atomicAdd(&bcnt[b], hist[b]);
}

// C2: tiny exclusive scan of 98 bucket counts -> bbase[0..NB] (bbase[NB]=NE), bcur
__global__ __launch_bounds__(128) void scan_bucket(
    const int* __restrict__ bcnt, int* __restrict__ bbase, int* __restrict__ bcur)
{
    __shared__ int s[128];
    const int t = threadIdx.x;
    s[t] = (t < NB) ? bcnt[t] : 0;
    __syncthreads();
    for (int off = 1; off < 128; off <<= 1) {
        int v = (t >= off) ? s[t - off] : 0;
        __syncthreads();
        s[t] += v;
        __syncthreads();
    }
    int excl = (t > 0) ? s[t - 1] : 0;
    if (t <= NB) bbase[t] = excl;       // bbase[NB] == total == NE
    if (t < NB)  bcur[t]  = excl;
}

// C3: bucket edges by dst>>9 into ebuf (contiguous per-bucket regions).
__global__ __launch_bounds__(256) void bucket_scatter(
    const int* __restrict__ src, const int* __restrict__ dst,
    int* __restrict__ bcur, int2* __restrict__ ebuf)
{
    __shared__ int hist[NB];
    __shared__ int base[NB];
    __shared__ int lcur[NB];
    const int t  = threadIdx.x;
    const int e0 = blockIdx.x * 2048 + t * 8;

    for (int b = t; b < NB; b += 256) { hist[b] = 0; lcur[b] = 0; }
    __syncthreads();

    int sj[8], dj[8];
    bool vj[8];
    #pragma unroll
    for (int j = 0; j < 8; ++j) {
        int e = e0 + j;
        vj[j] = (e < NE);
        if (vj[j]) {
            sj[j] = src[e];
            dj[j] = dst[e];
            atomicAdd(&hist[dj[j] >> 9], 1);
        }
    }
    __syncthreads();
    for (int b = t; b < NB; b += 256) {
        int c = hist[b];
        base[b] = c > 0 ? atomicAdd(&bcur[b], c) : 0;
    }
    __syncthreads();
    #pragma unroll
    for (int j = 0; j < 8; ++j) {
        if (vj[j]) {
            int b   = dj[j] >> 9;
            int off = atomicAdd(&lcur[b], 1);
            ebuf[(size_t)base[b] + off] = make_int2(sj[j], dj[j]);
        }
    }
}

// C4: one block per bucket: LDS histogram of 512 node-degrees, LDS scan,
// write rowptr (= bbase + local prefix) and fill csrsrc. All 98 blocks parallel.
__global__ __launch_bounds__(1024) void bucket_fill(
    const int* __restrict__ bbase, const int2* __restrict__ ebuf,
    int* __restrict__ rowptr, int* __restrict__ csrsrc)
{
    __shared__ int hist[512];
    __shared__ int excl[512];
    const int b    = blockIdx.x;
    const int n0   = b << 9;
    const int t    = threadIdx.x;
    const int base = bbase[b];
    const int cnt  = bbase[b + 1] - base;

    if (t < 512) hist[t] = 0;
    __syncthreads();
    for (int i = t; i < cnt; i += 1024)
        atomicAdd(&hist[ebuf[base + i].y - n0], 1);
    __syncthreads();
    if (t < 512) excl[t] = hist[t];
    __syncthreads();
    for (int off = 1; off < 512; off <<= 1) {
        int v = 0;
        if (t < 512 && t >= off) v = excl[t - off];
        __syncthreads();
        if (t < 512) excl[t] += v;
        __syncthreads();
    }
    if (t < 512) {
        int e = excl[t] - hist[t];          // exclusive prefix
        int n = n0 + t;
        if (n < NND) rowptr[n] = base + e;
        hist[t] = e;                        // reuse as cursor
    }
    if (b == NB - 1 && t == 0) rowptr[NND] = NE;
    __syncthreads();
    for (int i = t; i < cnt; i += 1024) {
        int2 ed = ebuf[base + i];
        int p = atomicAdd(&hist[ed.y - n0], 1);
        csrsrc[base + p] = ed.x;
    }
}

// ---------------- Gather-aggregate: one wave per destination node ----------------
__global__ __launch_bounds__(256) void gather_agg(
    const int* __restrict__ rowptr, const int* __restrict__ csrsrc,
    const float* __restrict__ el, const float* __restrict__ er,
    const unsigned int* __restrict__ featu,
    const float* __restrict__ hin_f32,          // layer1 residual (fs) or null
    const unsigned int* __restrict__ hin_hi,    // layer2 residual (hi/lo) or null
    const unsigned int* __restrict__ hin_lo,
    const float* __restrict__ bias,
    float* __restrict__ esum_out,
    float* __restrict__ hout_f32,               // layer2 out or null
    unsigned int* __restrict__ hhi_out,         // layer1 out or null
    unsigned int* __restrict__ hlo_out)
{
    const int wid  = (blockIdx.x * blockDim.x + threadIdx.x) >> 6;
    const int lane = threadIdx.x & 63;
    if (wid >= NND) return;
    const int n  = wid;
    const int h  = lane >> 3;   // head (softmax + feat dims)
    const int j8 = lane & 7;    // edge slot in chunk

    const float ern = er[n * NH + h];
    const int r0 = __builtin_amdgcn_readfirstlane(rowptr[n]);
    const int r1 = __builtin_amdgcn_readfirstlane(rowptr[n + 1]);

    float acc0 = 0.f, acc1 = 0.f, es = 0.f;

    const int nfull = r0 + ((r1 - r0) & ~7);
    int i = r0;
    for (; i < nfull; i += 8) {
        int   sv = csrsrc[i + j8];
        float w  = expf(lrelu(el[sv * NH + h] + ern));
        int sjs[8];
        #pragma unroll
        for (int j = 0; j < 8; ++j) sjs[j] = __shfl(sv, j);
        unsigned int vs[8];
        #pragma unroll
        for (int j = 0; j < 8; ++j) vs[j] = featu[(size_t)sjs[j] * 64 + lane];
        #pragma unroll
        for (int j = 0; j < 8; ++j) {
            float wj = __shfl(w, (lane & 56) | j);
            es  += wj;
            acc0 = fmaf(wj, __uint_as_float(vs[j] << 16), acc0);
            acc1 = fmaf(wj, __uint_as_float(vs[j] & 0xffff0000u), acc1);
        }
    }
    if (i < r1) {
        const int m = r1 - i;                              // 1..7, wave-uniform
        int idx = i + j8;
        int sv  = csrsrc[idx < r1 ? idx : (r1 - 1)];
        float w = 0.f;
        if (j8 < m) w = expf(lrelu(el[sv * NH + h] + ern));
        #pragma unroll
        for (int j = 0; j < 8; ++j) {
            if (j >= m) break;                             // uniform
            int   sj = __shfl(sv, j);
            float wj = __shfl(w, (lane & 56) | j);
            unsigned int v = featu[(size_t)sj * 64 + lane];
            es  += wj;
            acc0 = fmaf(wj, __uint_as_float(v << 16), acc0);
            acc1 = fmaf(wj, __uint_as_float(v & 0xffff0000u), acc1);
        }
    }

    if (j8 == 0) esum_out[n * NH + h] = es;
    const float inv = 1.f / fmaxf(es, 1e-9f);

    float h0, h1;
    if (hin_f32) {
        float2 hv = reinterpret_cast<const float2*>(hin_f32)[(size_t)n * 64 + lane];
        h0 = hv.x; h1 = hv.y;
    } else {
        unsigned int hiu = hin_hi[(size_t)n * 64 + lane];
        unsigned int lou = hin_lo[(size_t)n * 64 + lane];
        h0 = __uint_as_float(hiu << 16) + __uint_as_float(lou << 16);
        h1 = __uint_as_float(hiu & 0xffff0000u) + __uint_as_float(lou & 0xffff0000u);
    }
    float o0 = elu(fmaf(acc0, inv, h0 + bias[lane * 2]));
    float o1 = elu(fmaf(acc1, inv, h1 + bias[lane * 2 + 1]));

    if (hout_f32) {
        reinterpret_cast<float2*>(hout_f32)[(size_t)n * 64 + lane] = make_float2(o0, o1);
    } else {
        unsigned short hi0 = f2bf(o0), hi1 = f2bf(o1);
        unsigned short lo0 = f2bf(o0 - bf2f(hi0)), lo1 = f2bf(o1 - bf2f(hi1));
        hhi_out[(size_t)n * 64 + lane] = (unsigned int)hi0 | ((unsigned int)hi1 << 16);
        hlo_out[(size_t)n * 64 + lane] = (unsigned int)lo0 | ((unsigned int)lo1 << 16);
    }
}

// ---------------- alpha in original edge order (last layer only) ----------------
__global__ __launch_bounds__(256) void alpha_write(
    const int* __restrict__ src, const int* __restrict__ dst,
    const float* __restrict__ el, const float* __restrict__ er,
    const float* __restrict__ esum, float* __restrict__ aout)
{
    int tid = blockIdx.x * blockDim.x + threadIdx.x;
    if (tid >= NE * NH) return;
    int e = tid >> 3;
    int h = tid & 7;
    int s = src[e], d = dst[e];
    float x = lrelu(el[s * NH + h] + er[d * NH + h]);
    float a = expf(x) / fmaxf(esum[d * NH + h], 1e-9f);
    aout[(size_t)e * NH + h] = a;
}

extern "C" void kernel_launch(void* const* d_in, const int* in_sizes, int n_in,
                              void* d_out, int out_size, void* d_ws, size_t ws_size,
                              hipStream_t stream) {
    const float* fs   = (const float*)d_in[0];  // [2][N][128]
    const float* W    = (const float*)d_in[1];  // [2][2][128][128]
    const float* al   = (const float*)d_in[2];  // [2][2][8][16]
    const float* ar   = (const float*)d_in[3];  // [2][2][8][16]
    const float* bias = (const float*)d_in[4];  // [2][2][128]
    const int*   edges= (const int*)d_in[5];    // [2][2][E]

    float* out       = (float*)d_out;
    float* out_emb   = out;                              // [2][N][128]
    float* out_alpha = out + (size_t)2 * NND * EMB;      // [2][E][8]

    char* ws = (char*)d_ws;
    unsigned short* feat_bf = (unsigned short*)ws; ws += (size_t)NND * EMB * 2;
    unsigned short* hhi     = (unsigned short*)ws; ws += (size_t)NND * EMB * 2;
    unsigned short* hlo     = (unsigned short*)ws; ws += (size_t)NND * EMB * 2;
    float*          el      = (float*)ws;          ws += (size_t)NND * NH * 4;
    float*          er      = (float*)ws;          ws += (size_t)NND * NH * 4;
    float*          esum    = (float*)ws;          ws += (size_t)NND * NH * 4;
    int*            rowptr  = (int*)ws;            ws += (size_t)(NND + 1) * 4;
    int*            bcnt    = (int*)ws;            ws += (size_t)128 * 4;
    int*            bbase   = (int*)ws;            ws += (size_t)132 * 4;
    int*            bcur    = (int*)ws;            ws += (size_t)128 * 4;
    int*            csrsrc  = (int*)ws;            ws += (size_t)NE * 4;
    int2*           ebuf    = (int2*)ws;           ws += (size_t)NE * 8;
    unsigned short* bphi    = (unsigned short*)ws; ws += (size_t)16384 * 2;
    unsigned short* bplo    = (unsigned short*)ws; ws += (size_t)16384 * 2;

    unsigned int* featu = (unsigned int*)feat_bf;
    unsigned int* hhi_u = (unsigned int*)hhi;
    unsigned int* hlo_u = (unsigned int*)hlo;

    for (int p = 0; p < 2; ++p) {
        const int* src = edges + (size_t)p * 2 * NE;
        const int* dst = src + NE;

        hipMemsetAsync(bcnt, 0, (size_t)128 * 4, stream);
        bucket_count<<<(NE + 2047) / 2048, 256, 0, stream>>>(dst, bcnt);
        scan_bucket<<<1, 128, 0, stream>>>(bcnt, bbase, bcur);
        bucket_scatter<<<(NE + 2047) / 2048, 256, 0, stream>>>(src, dst, bcur, ebuf);
        bucket_fill<<<NB, 1024, 0, stream>>>(bbase, ebuf, rowptr, csrsrc);

        for (int l = 0; l < 2; ++l) {
            const float* fsp  = fs + (size_t)p * NND * EMB;
            const float* Wl   = W    + (size_t)(p * 2 + l) * EMB * EMB;
            const float* alv  = al   + (size_t)(p * 2 + l) * NH * HD;
            const float* arv  = ar   + (size_t)(p * 2 + l) * NH * HD;
            const float* bl   = bias + (size_t)(p * 2 + l) * EMB;

            wpack<<<8, 256, 0, stream>>>(Wl, bphi, bplo);
            if (l == 0)
                hsplit<<<NND * EMB / 8 / 256, 256, 0, stream>>>(fsp, hhi, hlo);

            mfma_gemm<<<(NND + 15) / 16, 256, 0, stream>>>(hhi, hlo, bphi, bplo, alv, arv, feat_bf, el, er);

            if (l == 0) {
                gather_agg<<<(NND + 3) / 4, 256, 0, stream>>>(
                    rowptr, csrsrc, el, er, featu,
                    fsp, nullptr, nullptr, bl, esum,
                    nullptr, hhi_u, hlo_u);
            } else {
                gather_agg<<<(NND + 3) / 4, 256, 0, stream>>>(
                    rowptr, csrsrc, el, er, featu,
                    nullptr, hhi_u, hlo_u, bl, esum,
                    out_emb + (size_t)p * NND * EMB, nullptr, nullptr);
                alpha_write<<<((size_t)NE * NH + 255) / 256, 256, 0, stream>>>(
                    src, dst, el, er, esum, out_alpha + (size_t)p * NE * NH);
            }
        }
    }
}

// Round 9
// 666.996 us; speedup vs baseline: 74.0143x; 1.0351x over previous
//
#include <hip/hip_runtime.h>
#include <hip/hip_bf16.h>

#define NND 50000
#define NE  1600000
#define EMB 128
#define NH  8
#define HD  16
#define NB  98            // ceil(50000/512) buckets of 512 dst nodes

typedef __attribute__((ext_vector_type(8))) short short8v;
typedef __attribute__((ext_vector_type(4))) float f32x4;

__device__ __forceinline__ float lrelu(float x) { return x > 0.f ? x : 0.2f * x; }
__device__ __forceinline__ float elu(float x)   { return x > 0.f ? x : expm1f(x); }

__device__ __forceinline__ unsigned short f2bf(float x) {
    __hip_bfloat16 b = __float2bfloat16(x);
    return *reinterpret_cast<unsigned short*>(&b);
}
__device__ __forceinline__ float bf2f(unsigned short u) {
    __hip_bfloat16 b = *reinterpret_cast<__hip_bfloat16*>(&u);
    return __bfloat162float(b);
}

// ---------------- split h into bf16 hi/lo (x ~= hi + lo) ----------------
__global__ __launch_bounds__(256) void hsplit(
    const float* __restrict__ hin, unsigned short* __restrict__ hhi, unsigned short* __restrict__ hlo)
{
    int idx = blockIdx.x * 256 + threadIdx.x;   // each handles 8 floats; grid exact
    const float4* h4 = reinterpret_cast<const float4*>(hin);
    float4 v0 = h4[(size_t)idx * 2];
    float4 v1 = h4[(size_t)idx * 2 + 1];
    float xs[8] = { v0.x, v0.y, v0.z, v0.w, v1.x, v1.y, v1.z, v1.w };
    unsigned short hi[8], lo[8];
    #pragma unroll
    for (int j = 0; j < 8; ++j) {
        hi[j] = f2bf(xs[j]);
        lo[j] = f2bf(xs[j] - bf2f(hi[j]));
    }
    *reinterpret_cast<uint4*>(hhi + (size_t)idx * 8) = *reinterpret_cast<uint4*>(hi);
    *reinterpret_cast<uint4*>(hlo + (size_t)idx * 8) = *reinterpret_cast<uint4*>(lo);
}

// ---------------- pack W into per-fragment bf16 hi/lo layout ----------------
__global__ __launch_bounds__(256) void wpack(
    const float* __restrict__ Wm, unsigned short* __restrict__ bphi, unsigned short* __restrict__ bplo)
{
    int s = blockIdx.x * 256 + threadIdx.x;   // grid 8 x 256 = 2048
    if (s >= 2048) return;
    int n    = s >> 8;
    int kt   = (s >> 6) & 3;
    int lane = s & 63;
    int col  = n * 16 + (lane & 15);
    int krow = kt * 32 + ((lane >> 4) << 3);
    #pragma unroll
    for (int j = 0; j < 8; ++j) {
        float x = Wm[(size_t)(krow + j) * EMB + col];
        unsigned short hi = f2bf(x);
        unsigned short lo = f2bf(x - bf2f(hi));
        bphi[(size_t)s * 8 + j] = hi;
        bplo[(size_t)s * 8 + j] = lo;
    }
}

// ---------------- MFMA GEMM: feat = h @ W (bf16x3), fused el/er ----------------
// Block 256 = 4 waves; wave w handles 16 rows x 32 cols (heads 2w, 2w+1).
__global__ __launch_bounds__(256) void mfma_gemm(
    const unsigned short* __restrict__ hhi, const unsigned short* __restrict__ hlo,
    const unsigned short* __restrict__ bphi, const unsigned short* __restrict__ bplo,
    const float* __restrict__ alv, const float* __restrict__ arv,
    unsigned short* __restrict__ feat_bf, float* __restrict__ el, float* __restrict__ er)
{
    const int lane = threadIdx.x & 63;
    const int wave = threadIdx.x >> 6;
    const int rowbase = blockIdx.x * 16;

    f32x4 acc[2];
    acc[0] = (f32x4){0.f, 0.f, 0.f, 0.f};
    acc[1] = (f32x4){0.f, 0.f, 0.f, 0.f};

    const int ar  = rowbase + (lane & 15);
    const int car = ar < NND ? ar : NND - 1;
    const int kofs = (lane >> 4) * 8;

    #pragma unroll
    for (int kt = 0; kt < 4; ++kt) {
        const int k0 = kt * 32 + kofs;
        short8v ah = *reinterpret_cast<const short8v*>(hhi + (size_t)car * EMB + k0);
        short8v av = *reinterpret_cast<const short8v*>(hlo + (size_t)car * EMB + k0);
        #pragma unroll
        for (int q = 0; q < 2; ++q) {
            const int nn = wave * 2 + q;
            const size_t bofs = ((size_t)(nn * 4 + kt) * 64 + lane) * 8;
            short8v bh = *reinterpret_cast<const short8v*>(bphi + bofs);
            short8v bl = *reinterpret_cast<const short8v*>(bplo + bofs);
            acc[q] = __builtin_amdgcn_mfma_f32_16x16x32_bf16(ah, bh, acc[q], 0, 0, 0);
            acc[q] = __builtin_amdgcn_mfma_f32_16x16x32_bf16(av, bh, acc[q], 0, 0, 0);
            acc[q] = __builtin_amdgcn_mfma_f32_16x16x32_bf16(ah, bl, acc[q], 0, 0, 0);
        }
    }

    const int colr = lane & 15;
    const int rgrp = lane >> 4;
    const int row0 = rowbase + rgrp * 4;
    #pragma unroll
    for (int q = 0; q < 2; ++q) {
        const int nn = wave * 2 + q;
        f32x4 a = acc[q];
        #pragma unroll
        for (int r = 0; r < 4; ++r) {
            if (row0 + r < NND)
                feat_bf[(size_t)(row0 + r) * EMB + nn * 16 + colr] = f2bf(a[r]);
        }
        const float alc = alv[nn * 16 + colr];
        const float arc = arv[nn * 16 + colr];
        float pl[4], pr[4];
        #pragma unroll
        for (int r = 0; r < 4; ++r) { pl[r] = a[r] * alc; pr[r] = a[r] * arc; }
        #pragma unroll
        for (int mask = 1; mask < 16; mask <<= 1) {
            #pragma unroll
            for (int r = 0; r < 4; ++r) {
                pl[r] += __shfl_xor(pl[r], mask);
                pr[r] += __shfl_xor(pr[r], mask);
            }
        }
        if (colr == 0) {
            #pragma unroll
            for (int r = 0; r < 4; ++r) {
                int row = row0 + r;
                if (row < NND) {
                    el[row * NH + nn] = pl[r];
                    er[row * NH + nn] = pr[r];
                }
            }
        }
    }
}

// ---------------- CSR build (per path) ----------------
// C1: per-bucket edge counts
__global__ __launch_bounds__(256) void bucket_count(
    const int* __restrict__ dst, int* __restrict__ bcnt)
{
    __shared__ int hist[NB];
    const int t = threadIdx.x;
    for (int b = t; b < NB; b += 256) hist[b] = 0;
    __syncthreads();
    const int e0 = blockIdx.x * 2048 + t * 8;
    #pragma unroll
    for (int j = 0; j < 8; ++j) {
        int e = e0 + j;
        if (e < NE) atomicAdd(&hist[dst[e] >> 9], 1);
    }
    __syncthreads();
    for (int b = t; b < NB; b += 256)
        if (hist[b]) atomicAdd(&bcnt[b], hist[b]);
}

// C2: tiny exclusive scan of 98 bucket counts
__global__ __launch_bounds__(128) void scan_bucket(
    const int* __restrict__ bcnt, int* __restrict__ bbase, int* __restrict__ bcur)
{
    __shared__ int s[128];
    const int t = threadIdx.x;
    s[t] = (t < NB) ? bcnt[t] : 0;
    __syncthreads();
    for (int off = 1; off < 128; off <<= 1) {
        int v = (t >= off) ? s[t - off] : 0;
        __syncthreads();
        s[t] += v;
        __syncthreads();
    }
    int excl = (t > 0) ? s[t - 1] : 0;
    if (t <= NB) bbase[t] = excl;
    if (t < NB)  bcur[t]  = excl;
}

// C3: bucket edges by dst>>9; pack (src<<9)|localdst into one int.
__global__ __launch_bounds__(256) void bucket_scatter(
    const int* __restrict__ src, const int* __restrict__ dst,
    int* __restrict__ bcur, int* __restrict__ ebuf)
{
    __shared__ int hist[NB];
    __shared__ int base[NB];
    __shared__ int lcur[NB];
    const int t  = threadIdx.x;
    const int e0 = blockIdx.x * 2048 + t * 8;

    for (int b = t; b < NB; b += 256) { hist[b] = 0; lcur[b] = 0; }
    __syncthreads();

    int sj[8], dj[8];
    bool vj[8];
    #pragma unroll
    for (int j = 0; j < 8; ++j) {
        int e = e0 + j;
        vj[j] = (e < NE);
        if (vj[j]) {
            sj[j] = src[e];
            dj[j] = dst[e];
            atomicAdd(&hist[dj[j] >> 9], 1);
        }
    }
    __syncthreads();
    for (int b = t; b < NB; b += 256) {
        int c = hist[b];
        base[b] = c > 0 ? atomicAdd(&bcur[b], c) : 0;
    }
    __syncthreads();
    #pragma unroll
    for (int j = 0; j < 8; ++j) {
        if (vj[j]) {
            int b   = dj[j] >> 9;
            int off = atomicAdd(&lcur[b], 1);
            ebuf[(size_t)base[b] + off] = (sj[j] << 9) | (dj[j] & 511);
        }
    }
}

// C4: one block per bucket: LDS histogram + scan -> rowptr, fill csrsrc.
__global__ __launch_bounds__(1024) void bucket_fill(
    const int* __restrict__ bbase, const int* __restrict__ ebuf,
    int* __restrict__ rowptr, int* __restrict__ csrsrc)
{
    __shared__ int hist[512];
    __shared__ int excl[512];
    const int b    = blockIdx.x;
    const int n0   = b << 9;
    const int t    = threadIdx.x;
    const int base = bbase[b];
    const int cnt  = bbase[b + 1] - base;

    if (t < 512) hist[t] = 0;
    __syncthreads();
    for (int i = t; i < cnt; i += 1024)
        atomicAdd(&hist[ebuf[base + i] & 511], 1);
    __syncthreads();
    if (t < 512) excl[t] = hist[t];
    __syncthreads();
    for (int off = 1; off < 512; off <<= 1) {
        int v = 0;
        if (t < 512 && t >= off) v = excl[t - off];
        __syncthreads();
        if (t < 512) excl[t] += v;
        __syncthreads();
    }
    if (t < 512) {
        int e = excl[t] - hist[t];
        int n = n0 + t;
        if (n < NND) rowptr[n] = base + e;
        hist[t] = e;
    }
    if (b == NB - 1 && t == 0) rowptr[NND] = NE;
    __syncthreads();
    for (int i = t; i < cnt; i += 1024) {
        int ed = ebuf[base + i];
        int p = atomicAdd(&hist[ed & 511], 1);
        csrsrc[base + p] = ed >> 9;
    }
}

// ---------------- Gather-aggregate: one wave per destination node ----------------
// Uniform (scalar) src-id loads, no shfl; every lane computes w via __expf;
// 16 feat gathers in flight per iteration.
__global__ __launch_bounds__(256) void gather_agg(
    const int* __restrict__ rowptr, const int* __restrict__ csrsrc,
    const float* __restrict__ el, const float* __restrict__ er,
    const unsigned int* __restrict__ featu,
    const float* __restrict__ hin_f32,          // layer1 residual (fs) or null
    const unsigned int* __restrict__ hin_hi,    // layer2 residual (hi/lo) or null
    const unsigned int* __restrict__ hin_lo,
    const float* __restrict__ bias,
    float* __restrict__ esum_out,
    float* __restrict__ hout_f32,               // layer2 out or null
    unsigned int* __restrict__ hhi_out,         // layer1 out or null
    unsigned int* __restrict__ hlo_out)
{
    const int wid  = (blockIdx.x * blockDim.x + threadIdx.x) >> 6;
    const int lane = threadIdx.x & 63;
    if (wid >= NND) return;
    const int n = wid;
    const int h = lane >> 3;

    const float ern = er[n * NH + h];
    const int r0 = __builtin_amdgcn_readfirstlane(rowptr[n]);
    const int r1 = __builtin_amdgcn_readfirstlane(rowptr[n + 1]);

    float acc0 = 0.f, acc1 = 0.f, es = 0.f;

    int i = r0;
    for (; i + 16 <= r1; i += 16) {
        int sj[16];
        #pragma unroll
        for (int j = 0; j < 16; ++j) sj[j] = csrsrc[i + j];          // uniform
        unsigned int vs[16];
        #pragma unroll
        for (int j = 0; j < 16; ++j) vs[j] = featu[(size_t)sj[j] * 64 + lane];
        float w[16];
        #pragma unroll
        for (int j = 0; j < 16; ++j) w[j] = __expf(lrelu(el[sj[j] * NH + h] + ern));
        #pragma unroll
        for (int j = 0; j < 16; ++j) {
            es  += w[j];
            acc0 = fmaf(w[j], __uint_as_float(vs[j] << 16), acc0);
            acc1 = fmaf(w[j], __uint_as_float(vs[j] & 0xffff0000u), acc1);
        }
    }
    if (i + 8 <= r1) {
        int sj[8];
        #pragma unroll
        for (int j = 0; j < 8; ++j) sj[j] = csrsrc[i + j];
        unsigned int vs[8];
        #pragma unroll
        for (int j = 0; j < 8; ++j) vs[j] = featu[(size_t)sj[j] * 64 + lane];
        #pragma unroll
        for (int j = 0; j < 8; ++j) {
            float w = __expf(lrelu(el[sj[j] * NH + h] + ern));
            es  += w;
            acc0 = fmaf(w, __uint_as_float(vs[j] << 16), acc0);
            acc1 = fmaf(w, __uint_as_float(vs[j] & 0xffff0000u), acc1);
        }
        i += 8;
    }
    for (; i < r1; ++i) {                                            // tail < 8
        int sj = csrsrc[i];
        unsigned int v = featu[(size_t)sj * 64 + lane];
        float w = __expf(lrelu(el[sj * NH + h] + ern));
        es  += w;
        acc0 = fmaf(w, __uint_as_float(v << 16), acc0);
        acc1 = fmaf(w, __uint_as_float(v & 0xffff0000u), acc1);
    }

    if ((lane & 7) == 0) esum_out[n * NH + h] = es;
    const float inv = 1.f / fmaxf(es, 1e-9f);

    float h0, h1;
    if (hin_f32) {
        float2 hv = reinterpret_cast<const float2*>(hin_f32)[(size_t)n * 64 + lane];
        h0 = hv.x; h1 = hv.y;
    } else {
        unsigned int hiu = hin_hi[(size_t)n * 64 + lane];
        unsigned int lou = hin_lo[(size_t)n * 64 + lane];
        h0 = __uint_as_float(hiu << 16) + __uint_as_float(lou << 16);
        h1 = __uint_as_float(hiu & 0xffff0000u) + __uint_as_float(lou & 0xffff0000u);
    }
    float o0 = elu(fmaf(acc0, inv, h0 + bias[lane * 2]));
    float o1 = elu(fmaf(acc1, inv, h1 + bias[lane * 2 + 1]));

    if (hout_f32) {
        reinterpret_cast<float2*>(hout_f32)[(size_t)n * 64 + lane] = make_float2(o0, o1);
    } else {
        unsigned short hi0 = f2bf(o0), hi1 = f2bf(o1);
        unsigned short lo0 = f2bf(o0 - bf2f(hi0)), lo1 = f2bf(o1 - bf2f(hi1));
        hhi_out[(size_t)n * 64 + lane] = (unsigned int)hi0 | ((unsigned int)hi1 << 16);
        hlo_out[(size_t)n * 64 + lane] = (unsigned int)lo0 | ((unsigned int)lo1 << 16);
    }
}

// ---------------- alpha in original edge order (last layer only) ----------------
__global__ __launch_bounds__(256) void alpha_write(
    const int* __restrict__ src, const int* __restrict__ dst,
    const float* __restrict__ el, const float* __restrict__ er,
    const float* __restrict__ esum, float* __restrict__ aout)
{
    int tid = blockIdx.x * blockDim.x + threadIdx.x;
    if (tid >= NE * NH) return;
    int e = tid >> 3;
    int h = tid & 7;
    int s = src[e], d = dst[e];
    float x = lrelu(el[s * NH + h] + er[d * NH + h]);
    float a = __expf(x) / fmaxf(esum[d * NH + h], 1e-9f);
    aout[(size_t)e * NH + h] = a;
}

extern "C" void kernel_launch(void* const* d_in, const int* in_sizes, int n_in,
                              void* d_out, int out_size, void* d_ws, size_t ws_size,
                              hipStream_t stream) {
    const float* fs   = (const float*)d_in[0];  // [2][N][128]
    const float* W    = (const float*)d_in[1];  // [2][2][128][128]
    const float* al   = (const float*)d_in[2];  // [2][2][8][16]
    const float* ar   = (const float*)d_in[3];  // [2][2][8][16]
    const float* bias = (const float*)d_in[4];  // [2][2][128]
    const int*   edges= (const int*)d_in[5];    // [2][2][E]

    float* out       = (float*)d_out;
    float* out_emb   = out;                              // [2][N][128]
    float* out_alpha = out + (size_t)2 * NND * EMB;      // [2][E][8]

    char* ws = (char*)d_ws;
    unsigned short* feat_bf = (unsigned short*)ws; ws += (size_t)NND * EMB * 2;
    unsigned short* hhi     = (unsigned short*)ws; ws += (size_t)NND * EMB * 2;
    unsigned short* hlo     = (unsigned short*)ws; ws += (size_t)NND * EMB * 2;
    float*          el      = (float*)ws;          ws += (size_t)NND * NH * 4;
    float*          er      = (float*)ws;          ws += (size_t)NND * NH * 4;
    float*          esum    = (float*)ws;          ws += (size_t)NND * NH * 4;
    int*            rowptr  = (int*)ws;            ws += (size_t)(NND + 1) * 4;
    int*            bcnt    = (int*)ws;            ws += (size_t)128 * 4;
    int*            bbase   = (int*)ws;            ws += (size_t)132 * 4;
    int*            bcur    = (int*)ws;            ws += (size_t)128 * 4;
    int*            csrsrc  = (int*)ws;            ws += (size_t)NE * 4;
    int*            ebuf    = (int*)ws;            ws += (size_t)NE * 4;
    unsigned short* bphi    = (unsigned short*)ws; ws += (size_t)16384 * 2;
    unsigned short* bplo    = (unsigned short*)ws; ws += (size_t)16384 * 2;

    unsigned int* featu = (unsigned int*)feat_bf;
    unsigned int* hhi_u = (unsigned int*)hhi;
    unsigned int* hlo_u = (unsigned int*)hlo;

    for (int p = 0; p < 2; ++p) {
        const int* src = edges + (size_t)p * 2 * NE;
        const int* dst = src + NE;

        hipMemsetAsync(bcnt, 0, (size_t)128 * 4, stream);
        bucket_count<<<(NE + 2047) / 2048, 256, 0, stream>>>(dst, bcnt);
        scan_bucket<<<1, 128, 0, stream>>>(bcnt, bbase, bcur);
        bucket_scatter<<<(NE + 2047) / 2048, 256, 0, stream>>>(src, dst, bcur, ebuf);
        bucket_fill<<<NB, 1024, 0, stream>>>(bbase, ebuf, rowptr, csrsrc);

        for (int l = 0; l < 2; ++l) {
            const float* fsp  = fs + (size_t)p * NND * EMB;
            const float* Wl   = W    + (size_t)(p * 2 + l) * EMB * EMB;
            const float* alv  = al   + (size_t)(p * 2 + l) * NH * HD;
            const float* arv  = ar   + (size_t)(p * 2 + l) * NH * HD;
            const float* bl   = bias + (size_t)(p * 2 + l) * EMB;

            wpack<<<8, 256, 0, stream>>>(Wl, bphi, bplo);
            if (l == 0)
                hsplit<<<NND * EMB / 8 / 256, 256, 0, stream>>>(fsp, hhi, hlo);

            mfma_gemm<<<(NND + 15) / 16, 256, 0, stream>>>(hhi, hlo, bphi, bplo, alv, arv, feat_bf, el, er);

            if (l == 0) {
                gather_agg<<<(NND + 3) / 4, 256, 0, stream>>>(
                    rowptr, csrsrc, el, er, featu,
                    fsp, nullptr, nullptr, bl, esum,
                    nullptr, hhi_u, hlo_u);
            } else {
                gather_agg<<<(NND + 3) / 4, 256, 0, stream>>>(
                    rowptr, csrsrc, el, er, featu,
                    nullptr, hhi_u, hlo_u, bl, esum,
                    out_emb + (size_t)p * NND * EMB, nullptr, nullptr);
                alpha_write<<<((size_t)NE * NH + 255) / 256, 256, 0, stream>>>(
                    src, dst, el, er, esum, out_alpha + (size_t)p * NE * NH);
            }
        }
    }
}

// Round 10
// 598.250 us; speedup vs baseline: 82.5194x; 1.1149x over previous
//
#include <hip/hip_runtime.h>
#include <hip/hip_bf16.h>

#define NND 50000
#define NE  1600000
#define EMB 128
#define NH  8
#define HD  16
#define NB  98            // ceil(50000/512) buckets of 512 dst nodes

typedef __attribute__((ext_vector_type(8))) short short8v;
typedef __attribute__((ext_vector_type(4))) float f32x4;

__device__ __forceinline__ float lrelu(float x) { return x > 0.f ? x : 0.2f * x; }
__device__ __forceinline__ float elu(float x)   { return x > 0.f ? x : expm1f(x); }

__device__ __forceinline__ unsigned short f2bf(float x) {
    __hip_bfloat16 b = __float2bfloat16(x);
    return *reinterpret_cast<unsigned short*>(&b);
}
__device__ __forceinline__ float bf2f(unsigned short u) {
    __hip_bfloat16 b = *reinterpret_cast<__hip_bfloat16*>(&u);
    return __bfloat162float(b);
}

// ---------------- pack all 4 W matrices into per-fragment bf16 hi/lo ----------------
// For matrix q: bp[q*2048 + (n*4+kt)*64+lane][j] = W_q[kt*32+(lane>>4)*8+j][n*16+(lane&15)]
__global__ __launch_bounds__(256) void wpack4(
    const float* __restrict__ W, unsigned short* __restrict__ bphi, unsigned short* __restrict__ bplo)
{
    int s = blockIdx.x * 256 + threadIdx.x;   // grid 32 x 256 = 8192 = 4*2048
    int q    = s >> 11;
    int sidx = s & 2047;
    int n    = sidx >> 8;
    int kt   = (sidx >> 6) & 3;
    int lane = sidx & 63;
    int col  = n * 16 + (lane & 15);
    int krow = kt * 32 + ((lane >> 4) << 3);
    const float* Wm = W + (size_t)q * EMB * EMB;
    #pragma unroll
    for (int j = 0; j < 8; ++j) {
        float x = Wm[(size_t)(krow + j) * EMB + col];
        unsigned short hi = f2bf(x);
        unsigned short lo = f2bf(x - bf2f(hi));
        bphi[(size_t)s * 8 + j] = hi;
        bplo[(size_t)s * 8 + j] = lo;
    }
}

// ---------------- MFMA GEMM (layer-1): A read as f32, split in-register ----------------
// Block 256 = 4 waves; wave w handles 16 rows x 32 cols (heads 2w, 2w+1).
__global__ __launch_bounds__(256) void mfma_gemm_f32(
    const float* __restrict__ hin,
    const unsigned short* __restrict__ bphi, const unsigned short* __restrict__ bplo,
    const float* __restrict__ alv, const float* __restrict__ arv,
    unsigned short* __restrict__ feat_bf, float* __restrict__ el, float* __restrict__ er)
{
    const int lane = threadIdx.x & 63;
    const int wave = threadIdx.x >> 6;
    const int rowbase = blockIdx.x * 16;

    f32x4 acc[2];
    acc[0] = (f32x4){0.f, 0.f, 0.f, 0.f};
    acc[1] = (f32x4){0.f, 0.f, 0.f, 0.f};

    const int ar  = rowbase + (lane & 15);
    const int car = ar < NND ? ar : NND - 1;
    const int kofs = (lane >> 4) * 8;

    #pragma unroll
    for (int kt = 0; kt < 4; ++kt) {
        const int k0 = kt * 32 + kofs;
        const float4* fr = reinterpret_cast<const float4*>(hin + (size_t)car * EMB + k0);
        float4 x0 = fr[0], x1 = fr[1];
        float xs[8] = { x0.x, x0.y, x0.z, x0.w, x1.x, x1.y, x1.z, x1.w };
        short8v ah, av;
        #pragma unroll
        for (int j = 0; j < 8; ++j) {
            unsigned short hi = f2bf(xs[j]);
            ah[j] = (short)hi;
            av[j] = (short)f2bf(xs[j] - bf2f(hi));
        }
        #pragma unroll
        for (int q = 0; q < 2; ++q) {
            const int nn = wave * 2 + q;
            const size_t bofs = ((size_t)(nn * 4 + kt) * 64 + lane) * 8;
            short8v bh = *reinterpret_cast<const short8v*>(bphi + bofs);
            short8v bl = *reinterpret_cast<const short8v*>(bplo + bofs);
            acc[q] = __builtin_amdgcn_mfma_f32_16x16x32_bf16(ah, bh, acc[q], 0, 0, 0);
            acc[q] = __builtin_amdgcn_mfma_f32_16x16x32_bf16(av, bh, acc[q], 0, 0, 0);
            acc[q] = __builtin_amdgcn_mfma_f32_16x16x32_bf16(ah, bl, acc[q], 0, 0, 0);
        }
    }

    const int colr = lane & 15;
    const int rgrp = lane >> 4;
    const int row0 = rowbase + rgrp * 4;
    #pragma unroll
    for (int q = 0; q < 2; ++q) {
        const int nn = wave * 2 + q;
        f32x4 a = acc[q];
        #pragma unroll
        for (int r = 0; r < 4; ++r) {
            if (row0 + r < NND)
                feat_bf[(size_t)(row0 + r) * EMB + nn * 16 + colr] = f2bf(a[r]);
        }
        const float alc = alv[nn * 16 + colr];
        const float arc = arv[nn * 16 + colr];
        float pl[4], pr[4];
        #pragma unroll
        for (int r = 0; r < 4; ++r) { pl[r] = a[r] * alc; pr[r] = a[r] * arc; }
        #pragma unroll
        for (int mask = 1; mask < 16; mask <<= 1) {
            #pragma unroll
            for (int r = 0; r < 4; ++r) {
                pl[r] += __shfl_xor(pl[r], mask);
                pr[r] += __shfl_xor(pr[r], mask);
            }
        }
        if (colr == 0) {
            #pragma unroll
            for (int r = 0; r < 4; ++r) {
                int row = row0 + r;
                if (row < NND) {
                    el[row * NH + nn] = pl[r];
                    er[row * NH + nn] = pr[r];
                }
            }
        }
    }
}

// ---------------- MFMA GEMM (layer-2): A from bf16 hi/lo arrays ----------------
__global__ __launch_bounds__(256) void mfma_gemm_bf(
    const unsigned short* __restrict__ hhi, const unsigned short* __restrict__ hlo,
    const unsigned short* __restrict__ bphi, const unsigned short* __restrict__ bplo,
    const float* __restrict__ alv, const float* __restrict__ arv,
    unsigned short* __restrict__ feat_bf, float* __restrict__ el, float* __restrict__ er)
{
    const int lane = threadIdx.x & 63;
    const int wave = threadIdx.x >> 6;
    const int rowbase = blockIdx.x * 16;

    f32x4 acc[2];
    acc[0] = (f32x4){0.f, 0.f, 0.f, 0.f};
    acc[1] = (f32x4){0.f, 0.f, 0.f, 0.f};

    const int ar  = rowbase + (lane & 15);
    const int car = ar < NND ? ar : NND - 1;
    const int kofs = (lane >> 4) * 8;

    #pragma unroll
    for (int kt = 0; kt < 4; ++kt) {
        const int k0 = kt * 32 + kofs;
        short8v ah = *reinterpret_cast<const short8v*>(hhi + (size_t)car * EMB + k0);
        short8v av = *reinterpret_cast<const short8v*>(hlo + (size_t)car * EMB + k0);
        #pragma unroll
        for (int q = 0; q < 2; ++q) {
            const int nn = wave * 2 + q;
            const size_t bofs = ((size_t)(nn * 4 + kt) * 64 + lane) * 8;
            short8v bh = *reinterpret_cast<const short8v*>(bphi + bofs);
            short8v bl = *reinterpret_cast<const short8v*>(bplo + bofs);
            acc[q] = __builtin_amdgcn_mfma_f32_16x16x32_bf16(ah, bh, acc[q], 0, 0, 0);
            acc[q] = __builtin_amdgcn_mfma_f32_16x16x32_bf16(av, bh, acc[q], 0, 0, 0);
            acc[q] = __builtin_amdgcn_mfma_f32_16x16x32_bf16(ah, bl, acc[q], 0, 0, 0);
        }
    }

    const int colr = lane & 15;
    const int rgrp = lane >> 4;
    const int row0 = rowbase + rgrp * 4;
    #pragma unroll
    for (int q = 0; q < 2; ++q) {
        const int nn = wave * 2 + q;
        f32x4 a = acc[q];
        #pragma unroll
        for (int r = 0; r < 4; ++r) {
            if (row0 + r < NND)
                feat_bf[(size_t)(row0 + r) * EMB + nn * 16 + colr] = f2bf(a[r]);
        }
        const float alc = alv[nn * 16 + colr];
        const float arc = arv[nn * 16 + colr];
        float pl[4], pr[4];
        #pragma unroll
        for (int r = 0; r < 4; ++r) { pl[r] = a[r] * alc; pr[r] = a[r] * arc; }
        #pragma unroll
        for (int mask = 1; mask < 16; mask <<= 1) {
            #pragma unroll
            for (int r = 0; r < 4; ++r) {
                pl[r] += __shfl_xor(pl[r], mask);
                pr[r] += __shfl_xor(pr[r], mask);
            }
        }
        if (colr == 0) {
            #pragma unroll
            for (int r = 0; r < 4; ++r) {
                int row = row0 + r;
                if (row < NND) {
                    el[row * NH + nn] = pl[r];
                    er[row * NH + nn] = pr[r];
                }
            }
        }
    }
}

// ---------------- CSR build: both paths in one pass (blockIdx.y = path) ----------------
__global__ __launch_bounds__(256) void bucket_count(
    const int* __restrict__ edges, int* __restrict__ bcnt)
{
    const int p = blockIdx.y;
    const int* dst = edges + (size_t)p * 2 * NE + NE;
    __shared__ int hist[NB];
    const int t = threadIdx.x;
    for (int b = t; b < NB; b += 256) hist[b] = 0;
    __syncthreads();
    const int e0 = blockIdx.x * 2048 + t * 8;
    #pragma unroll
    for (int j = 0; j < 8; ++j) {
        int e = e0 + j;
        if (e < NE) atomicAdd(&hist[dst[e] >> 9], 1);
    }
    __syncthreads();
    for (int b = t; b < NB; b += 256)
        if (hist[b]) atomicAdd(&bcnt[p * 128 + b], hist[b]);
}

// one block per path; 128-thread scan of 98 counts
__global__ __launch_bounds__(128) void scan_bucket(
    const int* __restrict__ bcnt, int* __restrict__ bbase, int* __restrict__ bcur)
{
    const int p = blockIdx.x;
    __shared__ int s[128];
    const int t = threadIdx.x;
    s[t] = (t < NB) ? bcnt[p * 128 + t] : 0;
    __syncthreads();
    for (int off = 1; off < 128; off <<= 1) {
        int v = (t >= off) ? s[t - off] : 0;
        __syncthreads();
        s[t] += v;
        __syncthreads();
    }
    int excl = (t > 0) ? s[t - 1] : 0;
    if (t <= NB) bbase[p * 128 + t] = excl;
    if (t < NB)  bcur[p * 128 + t]  = excl;
}

__global__ __launch_bounds__(256) void bucket_scatter(
    const int* __restrict__ edges, int* __restrict__ bcur, int* __restrict__ ebuf)
{
    const int p = blockIdx.y;
    const int* src = edges + (size_t)p * 2 * NE;
    const int* dst = src + NE;
    int* eb = ebuf + (size_t)p * NE;
    __shared__ int hist[NB];
    __shared__ int base[NB];
    __shared__ int lcur[NB];
    const int t  = threadIdx.x;
    const int e0 = blockIdx.x * 2048 + t * 8;

    for (int b = t; b < NB; b += 256) { hist[b] = 0; lcur[b] = 0; }
    __syncthreads();

    int sj[8], dj[8];
    bool vj[8];
    #pragma unroll
    for (int j = 0; j < 8; ++j) {
        int e = e0 + j;
        vj[j] = (e < NE);
        if (vj[j]) {
            sj[j] = src[e];
            dj[j] = dst[e];
            atomicAdd(&hist[dj[j] >> 9], 1);
        }
    }
    __syncthreads();
    for (int b = t; b < NB; b += 256) {
        int c = hist[b];
        base[b] = c > 0 ? atomicAdd(&bcur[p * 128 + b], c) : 0;
    }
    __syncthreads();
    #pragma unroll
    for (int j = 0; j < 8; ++j) {
        if (vj[j]) {
            int b   = dj[j] >> 9;
            int off = atomicAdd(&lcur[b], 1);
            eb[(size_t)base[b] + off] = (sj[j] << 9) | (dj[j] & 511);
        }
    }
}

__global__ __launch_bounds__(1024) void bucket_fill(
    const int* __restrict__ bbase, const int* __restrict__ ebuf,
    int* __restrict__ rowptr, int* __restrict__ csrsrc)
{
    const int p = blockIdx.y;
    const int* eb = ebuf + (size_t)p * NE;
    int* rp = rowptr + (size_t)p * (NND + 1);
    int* cs = csrsrc + (size_t)p * NE;
    __shared__ int hist[512];
    __shared__ int excl[512];
    const int b    = blockIdx.x;
    const int n0   = b << 9;
    const int t    = threadIdx.x;
    const int base = bbase[p * 128 + b];
    const int cnt  = bbase[p * 128 + b + 1] - base;

    if (t < 512) hist[t] = 0;
    __syncthreads();
    for (int i = t; i < cnt; i += 1024)
        atomicAdd(&hist[eb[base + i] & 511], 1);
    __syncthreads();
    if (t < 512) excl[t] = hist[t];
    __syncthreads();
    for (int off = 1; off < 512; off <<= 1) {
        int v = 0;
        if (t < 512 && t >= off) v = excl[t - off];
        __syncthreads();
        if (t < 512) excl[t] += v;
        __syncthreads();
    }
    if (t < 512) {
        int e = excl[t] - hist[t];
        int n = n0 + t;
        if (n < NND) rp[n] = base + e;
        hist[t] = e;
    }
    if (b == NB - 1 && t == 0) rp[NND] = NE;
    __syncthreads();
    for (int i = t; i < cnt; i += 1024) {
        int ed = eb[base + i];
        int q = atomicAdd(&hist[ed & 511], 1);
        cs[base + q] = ed >> 9;
    }
}

// ---------------- Gather-aggregate: one wave per destination node ----------------
__global__ __launch_bounds__(256) void gather_agg(
    const int* __restrict__ rowptr, const int* __restrict__ csrsrc,
    const float* __restrict__ el, const float* __restrict__ er,
    const unsigned int* __restrict__ featu,
    const float* __restrict__ hin_f32,          // layer1 residual (fs) or null
    const unsigned int* __restrict__ hin_hi,    // layer2 residual (hi/lo) or null
    const unsigned int* __restrict__ hin_lo,
    const float* __restrict__ bias,
    float* __restrict__ esum_out,
    float* __restrict__ hout_f32,               // layer2 out or null
    unsigned int* __restrict__ hhi_out,         // layer1 out or null
    unsigned int* __restrict__ hlo_out)
{
    const int wid  = (blockIdx.x * blockDim.x + threadIdx.x) >> 6;
    const int lane = threadIdx.x & 63;
    if (wid >= NND) return;
    const int n = wid;
    const int h = lane >> 3;

    const float ern = er[n * NH + h];
    const int r0 = __builtin_amdgcn_readfirstlane(rowptr[n]);
    const int r1 = __builtin_amdgcn_readfirstlane(rowptr[n + 1]);

    float acc0 = 0.f, acc1 = 0.f, es = 0.f;

    int i = r0;
    for (; i + 16 <= r1; i += 16) {
        int sj[16];
        #pragma unroll
        for (int j = 0; j < 16; ++j) sj[j] = csrsrc[i + j];          // uniform
        unsigned int vs[16];
        #pragma unroll
        for (int j = 0; j < 16; ++j) vs[j] = featu[(size_t)sj[j] * 64 + lane];
        float w[16];
        #pragma unroll
        for (int j = 0; j < 16; ++j) w[j] = __expf(lrelu(el[sj[j] * NH + h] + ern));
        #pragma unroll
        for (int j = 0; j < 16; ++j) {
            es  += w[j];
            acc0 = fmaf(w[j], __uint_as_float(vs[j] << 16), acc0);
            acc1 = fmaf(w[j], __uint_as_float(vs[j] & 0xffff0000u), acc1);
        }
    }
    if (i + 8 <= r1) {
        int sj[8];
        #pragma unroll
        for (int j = 0; j < 8; ++j) sj[j] = csrsrc[i + j];
        unsigned int vs[8];
        #pragma unroll
        for (int j = 0; j < 8; ++j) vs[j] = featu[(size_t)sj[j] * 64 + lane];
        #pragma unroll
        for (int j = 0; j < 8; ++j) {
            float w = __expf(lrelu(el[sj[j] * NH + h] + ern));
            es  += w;
            acc0 = fmaf(w, __uint_as_float(vs[j] << 16), acc0);
            acc1 = fmaf(w, __uint_as_float(vs[j] & 0xffff0000u), acc1);
        }
        i += 8;
    }
    for (; i < r1; ++i) {
        int sj = csrsrc[i];
        unsigned int v = featu[(size_t)sj * 64 + lane];
        float w = __expf(lrelu(el[sj * NH + h] + ern));
        es  += w;
        acc0 = fmaf(w, __uint_as_float(v << 16), acc0);
        acc1 = fmaf(w, __uint_as_float(v & 0xffff0000u), acc1);
    }

    if ((lane & 7) == 0) esum_out[n * NH + h] = es;
    const float inv = 1.f / fmaxf(es, 1e-9f);

    float h0, h1;
    if (hin_f32) {
        float2 hv = reinterpret_cast<const float2*>(hin_f32)[(size_t)n * 64 + lane];
        h0 = hv.x; h1 = hv.y;
    } else {
        unsigned int hiu = hin_hi[(size_t)n * 64 + lane];
        unsigned int lou = hin_lo[(size_t)n * 64 + lane];
        h0 = __uint_as_float(hiu << 16) + __uint_as_float(lou << 16);
        h1 = __uint_as_float(hiu & 0xffff0000u) + __uint_as_float(lou & 0xffff0000u);
    }
    float o0 = elu(fmaf(acc0, inv, h0 + bias[lane * 2]));
    float o1 = elu(fmaf(acc1, inv, h1 + bias[lane * 2 + 1]));

    if (hout_f32) {
        reinterpret_cast<float2*>(hout_f32)[(size_t)n * 64 + lane] = make_float2(o0, o1);
    } else {
        unsigned short hi0 = f2bf(o0), hi1 = f2bf(o1);
        unsigned short lo0 = f2bf(o0 - bf2f(hi0)), lo1 = f2bf(o1 - bf2f(hi1));
        hhi_out[(size_t)n * 64 + lane] = (unsigned int)hi0 | ((unsigned int)hi1 << 16);
        hlo_out[(size_t)n * 64 + lane] = (unsigned int)lo0 | ((unsigned int)lo1 << 16);
    }
}

// ---------------- alpha: one thread per edge, all 8 heads vectorized ----------------
__global__ __launch_bounds__(256) void alpha_write8(
    const int* __restrict__ src, const int* __restrict__ dst,
    const float* __restrict__ el, const float* __restrict__ er,
    const float* __restrict__ esum, float* __restrict__ aout)
{
    int e = blockIdx.x * 256 + threadIdx.x;
    if (e >= NE) return;
    int s = src[e], d = dst[e];
    const float4* el4 = reinterpret_cast<const float4*>(el + (size_t)s * 8);
    const float4* er4 = reinterpret_cast<const float4*>(er + (size_t)d * 8);
    const float4* es4 = reinterpret_cast<const float4*>(esum + (size_t)d * 8);
    float4 L0 = el4[0], L1 = el4[1];
    float4 R0 = er4[0], R1 = er4[1];
    float4 S0 = es4[0], S1 = es4[1];
    float4 a0, a1;
    a0.x = __fdividef(__expf(lrelu(L0.x + R0.x)), fmaxf(S0.x, 1e-9f));
    a0.y = __fdividef(__expf(lrelu(L0.y + R0.y)), fmaxf(S0.y, 1e-9f));
    a0.z = __fdividef(__expf(lrelu(L0.z + R0.z)), fmaxf(S0.z, 1e-9f));
    a0.w = __fdividef(__expf(lrelu(L0.w + R0.w)), fmaxf(S0.w, 1e-9f));
    a1.x = __fdividef(__expf(lrelu(L1.x + R1.x)), fmaxf(S1.x, 1e-9f));
    a1.y = __fdividef(__expf(lrelu(L1.y + R1.y)), fmaxf(S1.y, 1e-9f));
    a1.z = __fdividef(__expf(lrelu(L1.z + R1.z)), fmaxf(S1.z, 1e-9f));
    a1.w = __fdividef(__expf(lrelu(L1.w + R1.w)), fmaxf(S1.w, 1e-9f));
    float4* o4 = reinterpret_cast<float4*>(aout + (size_t)e * 8);
    o4[0] = a0;
    o4[1] = a1;
}

extern "C" void kernel_launch(void* const* d_in, const int* in_sizes, int n_in,
                              void* d_out, int out_size, void* d_ws, size_t ws_size,
                              hipStream_t stream) {
    const float* fs   = (const float*)d_in[0];  // [2][N][128]
    const float* W    = (const float*)d_in[1];  // [2][2][128][128]
    const float* al   = (const float*)d_in[2];  // [2][2][8][16]
    const float* ar   = (const float*)d_in[3];  // [2][2][8][16]
    const float* bias = (const float*)d_in[4];  // [2][2][128]
    const int*   edges= (const int*)d_in[5];    // [2][2][E]

    float* out       = (float*)d_out;
    float* out_emb   = out;                              // [2][N][128]
    float* out_alpha = out + (size_t)2 * NND * EMB;      // [2][E][8]

    char* ws = (char*)d_ws;
    auto take = [&](size_t bytes) {
        char* r = ws;
        ws += (bytes + 15) & ~(size_t)15;   // keep 16B alignment
        return r;
    };
    unsigned short* feat_bf = (unsigned short*)take((size_t)NND * EMB * 2);
    unsigned short* hhi     = (unsigned short*)take((size_t)NND * EMB * 2);
    unsigned short* hlo     = (unsigned short*)take((size_t)NND * EMB * 2);  // aliased by ebuf[2][NE]
    float*          el      = (float*)take((size_t)NND * NH * 4);
    float*          er      = (float*)take((size_t)NND * NH * 4);
    float*          esum    = (float*)take((size_t)NND * NH * 4);
    int*            rowptr  = (int*)take((size_t)2 * (NND + 1) * 4);
    int*            bcnt    = (int*)take((size_t)2 * 128 * 4);
    int*            bbase   = (int*)take((size_t)2 * 128 * 4);
    int*            bcur    = (int*)take((size_t)2 * 128 * 4);
    int*            csrsrc  = (int*)take((size_t)2 * NE * 4);
    unsigned short* bphi    = (unsigned short*)take((size_t)4 * 16384 * 2);
    unsigned short* bplo    = (unsigned short*)take((size_t)4 * 16384 * 2);

    int*          ebuf  = (int*)hlo;            // dead until gather l0 writes hlo
    unsigned int* featu = (unsigned int*)feat_bf;
    unsigned int* hhi_u = (unsigned int*)hhi;
    unsigned int* hlo_u = (unsigned int*)hlo;

    // --- CSR build for both paths (blockIdx.y = path) ---
    hipMemsetAsync(bcnt, 0, (size_t)2 * 128 * 4, stream);
    bucket_count<<<dim3((NE + 2047) / 2048, 2), 256, 0, stream>>>(edges, bcnt);
    scan_bucket<<<2, 128, 0, stream>>>(bcnt, bbase, bcur);
    bucket_scatter<<<dim3((NE + 2047) / 2048, 2), 256, 0, stream>>>(edges, bcur, ebuf);
    bucket_fill<<<dim3(NB, 2), 1024, 0, stream>>>(bbase, ebuf, rowptr, csrsrc);

    // --- all 4 weight packs in one launch ---
    wpack4<<<32, 256, 0, stream>>>(W, bphi, bplo);

    for (int p = 0; p < 2; ++p) {
        const int*   src = edges + (size_t)p * 2 * NE;
        const int*   dst = src + NE;
        const int*   rp  = rowptr + (size_t)p * (NND + 1);
        const int*   cs  = csrsrc + (size_t)p * NE;
        const float* fsp = fs + (size_t)p * NND * EMB;

        for (int l = 0; l < 2; ++l) {
            const int q = p * 2 + l;
            const unsigned short* bphi_q = bphi + (size_t)q * 16384;
            const unsigned short* bplo_q = bplo + (size_t)q * 16384;
            const float* alv = al   + (size_t)q * NH * HD;
            const float* arv = ar   + (size_t)q * NH * HD;
            const float* bl  = bias + (size_t)q * EMB;

            if (l == 0) {
                mfma_gemm_f32<<<(NND + 15) / 16, 256, 0, stream>>>(
                    fsp, bphi_q, bplo_q, alv, arv, feat_bf, el, er);
                gather_agg<<<(NND + 3) / 4, 256, 0, stream>>>(
                    rp, cs, el, er, featu,
                    fsp, nullptr, nullptr, bl, esum,
                    nullptr, hhi_u, hlo_u);
            } else {
                mfma_gemm_bf<<<(NND + 15) / 16, 256, 0, stream>>>(
                    hhi, hlo, bphi_q, bplo_q, alv, arv, feat_bf, el, er);
                gather_agg<<<(NND + 3) / 4, 256, 0, stream>>>(
                    rp, cs, el, er, featu,
                    nullptr, hhi_u, hlo_u, bl, esum,
                    out_emb + (size_t)p * NND * EMB, nullptr, nullptr);
                alpha_write8<<<(NE + 255) / 256, 256, 0, stream>>>(
                    src, dst, el, er, esum, out_alpha + (size_t)p * NE * NH);
            }
        }
    }
}

// Round 12
// 578.579 us; speedup vs baseline: 85.3250x; 1.0340x over previous
//
#include <hip/hip_runtime.h>
#include <hip/hip_bf16.h>

#define NND 50000
#define NE  1600000
#define EMB 128
#define NH  8
#define HD  16
#define NB  98            // ceil(50000/512) buckets of 512 dst nodes

typedef __attribute__((ext_vector_type(8))) short short8v;
typedef __attribute__((ext_vector_type(4))) float f32x4;

__device__ __forceinline__ float lrelu(float x) { return x > 0.f ? x : 0.2f * x; }
__device__ __forceinline__ float elu(float x)   { return x > 0.f ? x : expm1f(x); }

__device__ __forceinline__ unsigned short f2bf(float x) {
    __hip_bfloat16 b = __float2bfloat16(x);
    return *reinterpret_cast<unsigned short*>(&b);
}
__device__ __forceinline__ float bf2f(unsigned short u) {
    __hip_bfloat16 b = *reinterpret_cast<__hip_bfloat16*>(&u);
    return __bfloat162float(b);
}

// ---------------- pack all 4 W matrices into per-fragment bf16 hi/lo ----------------
__global__ __launch_bounds__(256) void wpack4(
    const float* __restrict__ W, unsigned short* __restrict__ bphi, unsigned short* __restrict__ bplo)
{
    int s = blockIdx.x * 256 + threadIdx.x;   // grid 32 x 256 = 8192 = 4*2048
    int q    = s >> 11;
    int sidx = s & 2047;
    int n    = sidx >> 8;
    int kt   = (sidx >> 6) & 3;
    int lane = sidx & 63;
    int col  = n * 16 + (lane & 15);
    int krow = kt * 32 + ((lane >> 4) << 3);
    const float* Wm = W + (size_t)q * EMB * EMB;
    #pragma unroll
    for (int j = 0; j < 8; ++j) {
        float x = Wm[(size_t)(krow + j) * EMB + col];
        unsigned short hi = f2bf(x);
        unsigned short lo = f2bf(x - bf2f(hi));
        bphi[(size_t)s * 8 + j] = hi;
        bplo[(size_t)s * 8 + j] = lo;
    }
}

// ---------------- shared GEMM epilogue ----------------
__device__ __forceinline__ void gemm_epilogue(
    f32x4 acc[2][2], int lane, int wave, int rowbase,
    const float* __restrict__ alv, const float* __restrict__ arv,
    unsigned short* __restrict__ feat_bf, float* __restrict__ el, float* __restrict__ er)
{
    const int colr = lane & 15;
    const int rgrp = lane >> 4;
    #pragma unroll
    for (int m = 0; m < 2; ++m) {
        const int row0 = rowbase + m * 16 + rgrp * 4;
        #pragma unroll
        for (int q = 0; q < 2; ++q) {
            const int nn = wave * 2 + q;
            f32x4 a = acc[m][q];
            #pragma unroll
            for (int r = 0; r < 4; ++r) {
                if (row0 + r < NND)
                    feat_bf[(size_t)(row0 + r) * EMB + nn * 16 + colr] = f2bf(a[r]);
            }
            const float alc = alv[nn * 16 + colr];
            const float arc = arv[nn * 16 + colr];
            float pl[4], pr[4];
            #pragma unroll
            for (int r = 0; r < 4; ++r) { pl[r] = a[r] * alc; pr[r] = a[r] * arc; }
            #pragma unroll
            for (int mask = 1; mask < 16; mask <<= 1) {
                #pragma unroll
                for (int r = 0; r < 4; ++r) {
                    pl[r] += __shfl_xor(pl[r], mask);
                    pr[r] += __shfl_xor(pr[r], mask);
                }
            }
            if (colr == 0) {
                #pragma unroll
                for (int r = 0; r < 4; ++r) {
                    int row = row0 + r;
                    if (row < NND) {
                        el[row * NH + nn] = pl[r];
                        er[row * NH + nn] = pr[r];
                    }
                }
            }
        }
    }
}

// ---------------- MFMA GEMM layer-1 (both paths): A = f32 fs, split in-register ----------------
// Wave: 32 rows x 32 cols (2 m-tiles x 2 heads); B fragments reused across m-tiles.
__global__ __launch_bounds__(256) void mfma_gemm_f32(
    const float* __restrict__ fs,
    const unsigned short* __restrict__ bphi_all, const unsigned short* __restrict__ bplo_all,
    const float* __restrict__ al_all, const float* __restrict__ ar_all,
    unsigned short* __restrict__ feat_all, float* __restrict__ el_all, float* __restrict__ er_all)
{
    const int p = blockIdx.y;
    const int q4 = p * 2;                    // layer 0 of path p
    const float* hin = fs + (size_t)p * NND * EMB;
    const unsigned short* bphi = bphi_all + (size_t)q4 * 16384;
    const unsigned short* bplo = bplo_all + (size_t)q4 * 16384;
    const float* alv = al_all + (size_t)q4 * NH * HD;
    const float* arv = ar_all + (size_t)q4 * NH * HD;
    unsigned short* feat_bf = feat_all + (size_t)p * NND * EMB;
    float* el = el_all + (size_t)p * NND * NH;
    float* er = er_all + (size_t)p * NND * NH;

    const int lane = threadIdx.x & 63;
    const int wave = threadIdx.x >> 6;
    const int rowbase = blockIdx.x * 32;

    f32x4 acc[2][2];
    #pragma unroll
    for (int m = 0; m < 2; ++m)
        #pragma unroll
        for (int q = 0; q < 2; ++q)
            acc[m][q] = (f32x4){0.f, 0.f, 0.f, 0.f};

    const int ar0 = rowbase + (lane & 15);
    const int ar1 = ar0 + 16;
    const int car0 = ar0 < NND ? ar0 : NND - 1;
    const int car1 = ar1 < NND ? ar1 : NND - 1;
    const int kofs = (lane >> 4) * 8;

    #pragma unroll
    for (int kt = 0; kt < 4; ++kt) {
        const int k0 = kt * 32 + kofs;
        short8v ah0, av0, ah1, av1;
        {
            const float4* fr = reinterpret_cast<const float4*>(hin + (size_t)car0 * EMB + k0);
            float4 x0 = fr[0], x1 = fr[1];
            float xs[8] = { x0.x, x0.y, x0.z, x0.w, x1.x, x1.y, x1.z, x1.w };
            #pragma unroll
            for (int j = 0; j < 8; ++j) {
                unsigned short hi = f2bf(xs[j]);
                ah0[j] = (short)hi;
                av0[j] = (short)f2bf(xs[j] - bf2f(hi));
            }
        }
        {
            const float4* fr = reinterpret_cast<const float4*>(hin + (size_t)car1 * EMB + k0);
            float4 x0 = fr[0], x1 = fr[1];
            float xs[8] = { x0.x, x0.y, x0.z, x0.w, x1.x, x1.y, x1.z, x1.w };
            #pragma unroll
            for (int j = 0; j < 8; ++j) {
                unsigned short hi = f2bf(xs[j]);
                ah1[j] = (short)hi;
                av1[j] = (short)f2bf(xs[j] - bf2f(hi));
            }
        }
        #pragma unroll
        for (int q = 0; q < 2; ++q) {
            const int nn = wave * 2 + q;
            const size_t bofs = ((size_t)(nn * 4 + kt) * 64 + lane) * 8;
            short8v bh = *reinterpret_cast<const short8v*>(bphi + bofs);
            short8v bl = *reinterpret_cast<const short8v*>(bplo + bofs);
            acc[0][q] = __builtin_amdgcn_mfma_f32_16x16x32_bf16(ah0, bh, acc[0][q], 0, 0, 0);
            acc[1][q] = __builtin_amdgcn_mfma_f32_16x16x32_bf16(ah1, bh, acc[1][q], 0, 0, 0);
            acc[0][q] = __builtin_amdgcn_mfma_f32_16x16x32_bf16(av0, bh, acc[0][q], 0, 0, 0);
            acc[1][q] = __builtin_amdgcn_mfma_f32_16x16x32_bf16(av1, bh, acc[1][q], 0, 0, 0);
            acc[0][q] = __builtin_amdgcn_mfma_f32_16x16x32_bf16(ah0, bl, acc[0][q], 0, 0, 0);
            acc[1][q] = __builtin_amdgcn_mfma_f32_16x16x32_bf16(ah1, bl, acc[1][q], 0, 0, 0);
        }
    }
    gemm_epilogue(acc, lane, wave, rowbase, alv, arv, feat_bf, el, er);
}

// ---------------- MFMA GEMM layer-2 (both paths): A = bf16 hi/lo ----------------
__global__ __launch_bounds__(256) void mfma_gemm_bf(
    const unsigned short* __restrict__ hhi_all, const unsigned short* __restrict__ hlo_all,
    const unsigned short* __restrict__ bphi_all, const unsigned short* __restrict__ bplo_all,
    const float* __restrict__ al_all, const float* __restrict__ ar_all,
    unsigned short* __restrict__ feat_all, float* __restrict__ el_all, float* __restrict__ er_all)
{
    const int p = blockIdx.y;
    const int q4 = p * 2 + 1;                // layer 1 of path p
    const unsigned short* hhi = hhi_all + (size_t)p * NND * EMB;
    const unsigned short* hlo = hlo_all + (size_t)p * NND * EMB;
    const unsigned short* bphi = bphi_all + (size_t)q4 * 16384;
    const unsigned short* bplo = bplo_all + (size_t)q4 * 16384;
    const float* alv = al_all + (size_t)q4 * NH * HD;
    const float* arv = ar_all + (size_t)q4 * NH * HD;
    unsigned short* feat_bf = feat_all + (size_t)p * NND * EMB;
    float* el = el_all + (size_t)p * NND * NH;
    float* er = er_all + (size_t)p * NND * NH;

    const int lane = threadIdx.x & 63;
    const int wave = threadIdx.x >> 6;
    const int rowbase = blockIdx.x * 32;

    f32x4 acc[2][2];
    #pragma unroll
    for (int m = 0; m < 2; ++m)
        #pragma unroll
        for (int q = 0; q < 2; ++q)
            acc[m][q] = (f32x4){0.f, 0.f, 0.f, 0.f};

    const int ar0 = rowbase + (lane & 15);
    const int ar1 = ar0 + 16;
    const int car0 = ar0 < NND ? ar0 : NND - 1;
    const int car1 = ar1 < NND ? ar1 : NND - 1;
    const int kofs = (lane >> 4) * 8;

    #pragma unroll
    for (int kt = 0; kt < 4; ++kt) {
        const int k0 = kt * 32 + kofs;
        short8v ah0 = *reinterpret_cast<const short8v*>(hhi + (size_t)car0 * EMB + k0);
        short8v av0 = *reinterpret_cast<const short8v*>(hlo + (size_t)car0 * EMB + k0);
        short8v ah1 = *reinterpret_cast<const short8v*>(hhi + (size_t)car1 * EMB + k0);
        short8v av1 = *reinterpret_cast<const short8v*>(hlo + (size_t)car1 * EMB + k0);
        #pragma unroll
        for (int q = 0; q < 2; ++q) {
            const int nn = wave * 2 + q;
            const size_t bofs = ((size_t)(nn * 4 + kt) * 64 + lane) * 8;
            short8v bh = *reinterpret_cast<const short8v*>(bphi + bofs);
            short8v bl = *reinterpret_cast<const short8v*>(bplo + bofs);
            acc[0][q] = __builtin_amdgcn_mfma_f32_16x16x32_bf16(ah0, bh, acc[0][q], 0, 0, 0);
            acc[1][q] = __builtin_amdgcn_mfma_f32_16x16x32_bf16(ah1, bh, acc[1][q], 0, 0, 0);
            acc[0][q] = __builtin_amdgcn_mfma_f32_16x16x32_bf16(av0, bh, acc[0][q], 0, 0, 0);
            acc[1][q] = __builtin_amdgcn_mfma_f32_16x16x32_bf16(av1, bh, acc[1][q], 0, 0, 0);
            acc[0][q] = __builtin_amdgcn_mfma_f32_16x16x32_bf16(ah0, bl, acc[0][q], 0, 0, 0);
            acc[1][q] = __builtin_amdgcn_mfma_f32_16x16x32_bf16(ah1, bl, acc[1][q], 0, 0, 0);
        }
    }
    gemm_epilogue(acc, lane, wave, rowbase, alv, arv, feat_bf, el, er);
}

// ---------------- CSR build: both paths (blockIdx.y = path) ----------------
__global__ __launch_bounds__(256) void bucket_count(
    const int* __restrict__ edges, int* __restrict__ bcnt)
{
    const int p = blockIdx.y;
    const int* dst = edges + (size_t)p * 2 * NE + NE;
    __shared__ int hist[NB];
    const int t = threadIdx.x;
    for (int b = t; b < NB; b += 256) hist[b] = 0;
    __syncthreads();
    const int e0 = blockIdx.x * 2048 + t * 8;
    #pragma unroll
    for (int j = 0; j < 8; ++j) {
        int e = e0 + j;
        if (e < NE) atomicAdd(&hist[dst[e] >> 9], 1);
    }
    __syncthreads();
    for (int b = t; b < NB; b += 256)
        if (hist[b]) atomicAdd(&bcnt[p * 128 + b], hist[b]);
}

__global__ __launch_bounds__(128) void scan_bucket(
    const int* __restrict__ bcnt, int* __restrict__ bbase, int* __restrict__ bcur)
{
    const int p = blockIdx.x;
    __shared__ int s[128];
    const int t = threadIdx.x;
    s[t] = (t < NB) ? bcnt[p * 128 + t] : 0;
    __syncthreads();
    for (int off = 1; off < 128; off <<= 1) {
        int v = (t >= off) ? s[t - off] : 0;
        __syncthreads();
        s[t] += v;
        __syncthreads();
    }
    int excl = (t > 0) ? s[t - 1] : 0;
    if (t <= NB) bbase[p * 128 + t] = excl;
    if (t < NB)  bcur[p * 128 + t]  = excl;
}

__global__ __launch_bounds__(256) void bucket_scatter(
    const int* __restrict__ edges, int* __restrict__ bcur, int* __restrict__ ebuf)
{
    const int p = blockIdx.y;
    const int* src = edges + (size_t)p * 2 * NE;
    const int* dst = src + NE;
    int* eb = ebuf + (size_t)p * NE;
    __shared__ int hist[NB];
    __shared__ int base[NB];
    __shared__ int lcur[NB];
    const int t  = threadIdx.x;
    const int e0 = blockIdx.x * 2048 + t * 8;

    for (int b = t; b < NB; b += 256) { hist[b] = 0; lcur[b] = 0; }
    __syncthreads();

    int sj[8], dj[8];
    bool vj[8];
    #pragma unroll
    for (int j = 0; j < 8; ++j) {
        int e = e0 + j;
        vj[j] = (e < NE);
        if (vj[j]) {
            sj[j] = src[e];
            dj[j] = dst[e];
            atomicAdd(&hist[dj[j] >> 9], 1);
        }
    }
    __syncthreads();
    for (int b = t; b < NB; b += 256) {
        int c = hist[b];
        base[b] = c > 0 ? atomicAdd(&bcur[p * 128 + b], c) : 0;
    }
    __syncthreads();
    #pragma unroll
    for (int j = 0; j < 8; ++j) {
        if (vj[j]) {
            int b   = dj[j] >> 9;
            int off = atomicAdd(&lcur[b], 1);
            eb[(size_t)base[b] + off] = (sj[j] << 9) | (dj[j] & 511);
        }
    }
}

__global__ __launch_bounds__(1024) void bucket_fill(
    const int* __restrict__ bbase, const int* __restrict__ ebuf,
    int* __restrict__ rowptr, int* __restrict__ csrsrc)
{
    const int p = blockIdx.y;
    const int* eb = ebuf + (size_t)p * NE;
    int* rp = rowptr + (size_t)p * (NND + 1);
    int* cs = csrsrc + (size_t)p * NE;
    __shared__ int hist[512];
    __shared__ int excl[512];
    const int b    = blockIdx.x;
    const int n0   = b << 9;
    const int t    = threadIdx.x;
    const int base = bbase[p * 128 + b];
    const int cnt  = bbase[p * 128 + b + 1] - base;

    if (t < 512) hist[t] = 0;
    __syncthreads();
    for (int i = t; i < cnt; i += 1024)
        atomicAdd(&hist[eb[base + i] & 511], 1);
    __syncthreads();
    if (t < 512) excl[t] = hist[t];
    __syncthreads();
    for (int off = 1; off < 512; off <<= 1) {
        int v = 0;
        if (t < 512 && t >= off) v = excl[t - off];
        __syncthreads();
        if (t < 512) excl[t] += v;
        __syncthreads();
    }
    if (t < 512) {
        int e = excl[t] - hist[t];
        int n = n0 + t;
        if (n < NND) rp[n] = base + e;
        hist[t] = e;
    }
    if (b == NB - 1 && t == 0) rp[NND] = NE;
    __syncthreads();
    for (int i = t; i < cnt; i += 1024) {
        int ed = eb[base + i];
        int q = atomicAdd(&hist[ed & 511], 1);
        cs[base + q] = ed >> 9;
    }
}

// ---------------- Gather-aggregate (both paths): one wave per destination node ----------------
__global__ __launch_bounds__(256) void gather_agg(
    const int* __restrict__ rowptr_all, const int* __restrict__ csrsrc_all,
    const float* __restrict__ el_all, const float* __restrict__ er_all,
    const unsigned int* __restrict__ feat_all,
    const float* __restrict__ fs,               // layer0 residual
    const unsigned int* __restrict__ hhi_all,   // l0: out; l1: residual
    const unsigned int* __restrict__ hlo_all,
    const float* __restrict__ bias_all,
    float* __restrict__ esum_all,
    float* __restrict__ out_emb,                // layer1 out
    int layer)
{
    const int p    = blockIdx.y;
    const int wid  = (blockIdx.x * blockDim.x + threadIdx.x) >> 6;
    const int lane = threadIdx.x & 63;
    if (wid >= NND) return;
    const int n = wid;
    const int h = lane >> 3;

    const int* rowptr = rowptr_all + (size_t)p * (NND + 1);
    const int* csrsrc = csrsrc_all + (size_t)p * NE;
    const float* el   = el_all + (size_t)p * NND * NH;
    const float* er   = er_all + (size_t)p * NND * NH;
    const unsigned int* featu = feat_all + (size_t)p * NND * 64;
    const float* bias = bias_all + (size_t)(p * 2 + layer) * EMB;

    const float ern = er[n * NH + h];
    const int r0 = __builtin_amdgcn_readfirstlane(rowptr[n]);
    const int r1 = __builtin_amdgcn_readfirstlane(rowptr[n + 1]);

    float acc0 = 0.f, acc1 = 0.f, es = 0.f;

    int i = r0;
    for (; i + 16 <= r1; i += 16) {
        int sj[16];
        #pragma unroll
        for (int j = 0; j < 16; ++j) sj[j] = csrsrc[i + j];          // uniform
        unsigned int vs[16];
        #pragma unroll
        for (int j = 0; j < 16; ++j) vs[j] = featu[(size_t)sj[j] * 64 + lane];
        float w[16];
        #pragma unroll
        for (int j = 0; j < 16; ++j) w[j] = __expf(lrelu(el[sj[j] * NH + h] + ern));
        #pragma unroll
        for (int j = 0; j < 16; ++j) {
            es  += w[j];
            acc0 = fmaf(w[j], __uint_as_float(vs[j] << 16), acc0);
            acc1 = fmaf(w[j], __uint_as_float(vs[j] & 0xffff0000u), acc1);
        }
    }
    if (i + 8 <= r1) {
        int sj[8];
        #pragma unroll
        for (int j = 0; j < 8; ++j) sj[j] = csrsrc[i + j];
        unsigned int vs[8];
        #pragma unroll
        for (int j = 0; j < 8; ++j) vs[j] = featu[(size_t)sj[j] * 64 + lane];
        #pragma unroll
        for (int j = 0; j < 8; ++j) {
            float w = __expf(lrelu(el[sj[j] * NH + h] + ern));
            es  += w;
            acc0 = fmaf(w, __uint_as_float(vs[j] << 16), acc0);
            acc1 = fmaf(w, __uint_as_float(vs[j] & 0xffff0000u), acc1);
        }
        i += 8;
    }
    for (; i < r1; ++i) {
        int sj = csrsrc[i];
        unsigned int v = featu[(size_t)sj * 64 + lane];
        float w = __expf(lrelu(el[sj * NH + h] + ern));
        es  += w;
        acc0 = fmaf(w, __uint_as_float(v << 16), acc0);
        acc1 = fmaf(w, __uint_as_float(v & 0xffff0000u), acc1);
    }

    if ((lane & 7) == 0) esum_all[((size_t)p * NND + n) * NH + h] = es;
    const float inv = 1.f / fmaxf(es, 1e-9f);

    float h0, h1;
    if (layer == 0) {
        float2 hv = reinterpret_cast<const float2*>(fs + (size_t)p * NND * EMB)[(size_t)n * 64 + lane];
        h0 = hv.x; h1 = hv.y;
    } else {
        unsigned int hiu = hhi_all[((size_t)p * NND + n) * 64 + lane];
        unsigned int lou = hlo_all[((size_t)p * NND + n) * 64 + lane];
        h0 = __uint_as_float(hiu << 16) + __uint_as_float(lou << 16);
        h1 = __uint_as_float(hiu & 0xffff0000u) + __uint_as_float(lou & 0xffff0000u);
    }
    float o0 = elu(fmaf(acc0, inv, h0 + bias[lane * 2]));
    float o1 = elu(fmaf(acc1, inv, h1 + bias[lane * 2 + 1]));

    if (layer == 1) {
        reinterpret_cast<float2*>(out_emb + (size_t)p * NND * EMB)[(size_t)n * 64 + lane] =
            make_float2(o0, o1);
    } else {
        unsigned short hi0 = f2bf(o0), hi1 = f2bf(o1);
        unsigned short lo0 = f2bf(o0 - bf2f(hi0)), lo1 = f2bf(o1 - bf2f(hi1));
        const size_t idx = ((size_t)p * NND + n) * 64 + lane;
        const_cast<unsigned int*>(hhi_all)[idx] = (unsigned int)hi0 | ((unsigned int)hi1 << 16);
        const_cast<unsigned int*>(hlo_all)[idx] = (unsigned int)lo0 | ((unsigned int)lo1 << 16);
    }
}

// ---------------- alpha (both paths): one thread per edge, all 8 heads ----------------
__global__ __launch_bounds__(256) void alpha_write8(
    const int* __restrict__ edges,
    const float* __restrict__ el_all, const float* __restrict__ er_all,
    const float* __restrict__ esum_all, float* __restrict__ out_alpha)
{
    const int p = blockIdx.y;
    int e = blockIdx.x * 256 + threadIdx.x;
    if (e >= NE) return;
    const int* src = edges + (size_t)p * 2 * NE;
    const int* dst = src + NE;
    const float* el   = el_all   + (size_t)p * NND * NH;
    const float* er   = er_all   + (size_t)p * NND * NH;
    const float* esum = esum_all + (size_t)p * NND * NH;
    int s = src[e], d = dst[e];
    const float4* el4 = reinterpret_cast<const float4*>(el + (size_t)s * 8);
    const float4* er4 = reinterpret_cast<const float4*>(er + (size_t)d * 8);
    const float4* es4 = reinterpret_cast<const float4*>(esum + (size_t)d * 8);
    float4 L0 = el4[0], L1 = el4[1];
    float4 R0 = er4[0], R1 = er4[1];
    float4 S0 = es4[0], S1 = es4[1];
    float4 a0, a1;
    a0.x = __fdividef(__expf(lrelu(L0.x + R0.x)), fmaxf(S0.x, 1e-9f));
    a0.y = __fdividef(__expf(lrelu(L0.y + R0.y)), fmaxf(S0.y, 1e-9f));
    a0.z = __fdividef(__expf(lrelu(L0.z + R0.z)), fmaxf(S0.z, 1e-9f));
    a0.w = __fdividef(__expf(lrelu(L0.w + R0.w)), fmaxf(S0.w, 1e-9f));
    a1.x = __fdividef(__expf(lrelu(L1.x + R1.x)), fmaxf(S1.x, 1e-9f));
    a1.y = __fdividef(__expf(lrelu(L1.y + R1.y)), fmaxf(S1.y, 1e-9f));
    a1.z = __fdividef(__expf(lrelu(L1.z + R1.z)), fmaxf(S1.z, 1e-9f));
    a1.w = __fdividef(__expf(lrelu(L1.w + R1.w)), fmaxf(S1.w, 1e-9f));
    float4* o4 = reinterpret_cast<float4*>(out_alpha + ((size_t)p * NE + e) * 8);
    o4[0] = a0;
    o4[1] = a1;
}

extern "C" void kernel_launch(void* const* d_in, const int* in_sizes, int n_in,
                              void* d_out, int out_size, void* d_ws, size_t ws_size,
                              hipStream_t stream) {
    const float* fs   = (const float*)d_in[0];  // [2][N][128]
    const float* W    = (const float*)d_in[1];  // [2][2][128][128]
    const float* al   = (const float*)d_in[2];  // [2][2][8][16]
    const float* ar   = (const float*)d_in[3];  // [2][2][8][16]
    const float* bias = (const float*)d_in[4];  // [2][2][128]
    const int*   edges= (const int*)d_in[5];    // [2][2][E]

    float* out       = (float*)d_out;
    float* out_emb   = out;                              // [2][N][128]
    float* out_alpha = out + (size_t)2 * NND * EMB;      // [2][E][8]

    char* ws = (char*)d_ws;
    auto take = [&](size_t bytes) {
        char* r = ws;
        ws += (bytes + 15) & ~(size_t)15;
        return r;
    };
    unsigned short* feat_bf = (unsigned short*)take((size_t)2 * NND * EMB * 2);  // [2][N][128]
    unsigned short* hhi     = (unsigned short*)take((size_t)2 * NND * EMB * 2);
    unsigned short* hlo     = (unsigned short*)take((size_t)2 * NND * EMB * 2);  // ebuf aliases here
    float*          el      = (float*)take((size_t)2 * NND * NH * 4);
    float*          er      = (float*)take((size_t)2 * NND * NH * 4);
    float*          esum    = (float*)take((size_t)2 * NND * NH * 4);
    int*            rowptr  = (int*)take((size_t)2 * (NND + 1) * 4);
    int*            bcnt    = (int*)take((size_t)2 * 128 * 4);
    int*            bbase   = (int*)take((size_t)2 * 128 * 4);
    int*            bcur    = (int*)take((size_t)2 * 128 * 4);
    int*            csrsrc  = (int*)take((size_t)2 * NE * 4);
    unsigned short* bphi    = (unsigned short*)take((size_t)4 * 16384 * 2);
    unsigned short* bplo    = (unsigned short*)take((size_t)4 * 16384 * 2);

    int*          ebuf  = (int*)hlo;            // dead until gather l0 writes hlo
    unsigned int* featu = (unsigned int*)feat_bf;
    unsigned int* hhi_u = (unsigned int*)hhi;
    unsigned int* hlo_u = (unsigned int*)hlo;

    // --- CSR build, both paths ---
    hipMemsetAsync(bcnt, 0, (size_t)2 * 128 * 4, stream);
    bucket_count<<<dim3((NE + 2047) / 2048, 2), 256, 0, stream>>>(edges, bcnt);
    scan_bucket<<<2, 128, 0, stream>>>(bcnt, bbase, bcur);
    bucket_scatter<<<dim3((NE + 2047) / 2048, 2), 256, 0, stream>>>(edges, bcur, ebuf);
    bucket_fill<<<dim3(NB, 2), 1024, 0, stream>>>(bbase, ebuf, rowptr, csrsrc);

    // --- weights ---
    wpack4<<<32, 256, 0, stream>>>(W, bphi, bplo);

    // --- layer 0 (both paths per launch) ---
    mfma_gemm_f32<<<dim3((NND + 31) / 32, 2), 256, 0, stream>>>(
        fs, bphi, bplo, al, ar, feat_bf, el, er);
    gather_agg<<<dim3((NND + 3) / 4, 2), 256, 0, stream>>>(
        rowptr, csrsrc, el, er, featu, fs, hhi_u, hlo_u, bias, esum, nullptr, 0);

    // --- layer 1 (both paths per launch) ---
    mfma_gemm_bf<<<dim3((NND + 31) / 32, 2), 256, 0, stream>>>(
        hhi, hlo, bphi, bplo, al, ar, feat_bf, el, er);
    gather_agg<<<dim3((NND + 3) / 4, 2), 256, 0, stream>>>(
        rowptr, csrsrc, el, er, featu, fs, hhi_u, hlo_u, bias, esum, out_emb, 1);
    alpha_write8<<<dim3((NE + 255) / 256, 2), 256, 0, stream>>>(
        edges, el, er, esum, out_alpha);
}